// Round 3
// baseline (361.238 us; speedup 1.0000x reference)
//
#include <hip/hip_runtime.h>
#include <math.h>

// =====================================================================
// 3-layer GAT (PyG GATConv) on MI355X.
// R11: latency-optimized aggregation.
//  - agg_m4 fast path (deg<=16, ~99% of nodes): csr read once, ALL value
//    gathers issued before the softmax shuffle chain (16 outstanding
//    loads hide under the reductions); exact softmax (max is final, no
//    online rescale). Slow path (deg>16): two-phase stats-then-gather
//    with 16-deep hoisted loads per chunk.
//  - gemm_async unchanged from R10 (B dbuf global_load_lds + A reg
//    prefetch). Aggregates gather bf16, fp32 softmax/accum.
// =====================================================================

#define NEG_SLOPE 0.2f

typedef unsigned short u16;
typedef short bf16x8 __attribute__((ext_vector_type(8)));
typedef float floatx4 __attribute__((ext_vector_type(4)));

__device__ __forceinline__ float b2f(u16 u) {
    return __uint_as_float(((unsigned int)u) << 16);
}
__device__ __forceinline__ u16 f2b(float f) {
    unsigned int u = __float_as_uint(f);
    unsigned int r = (u + 0x7fffu + ((u >> 16) & 1u)) >> 16;   // RNE
    return (u16)r;
}

// async 16B global -> LDS (DMA, no VGPR round-trip). LDS dest must be
// wave-uniform base; HW adds lane*16. Global source is per-lane.
__device__ __forceinline__ void load16(const u16* g, u16* l) {
    __builtin_amdgcn_global_load_lds(
        (const __attribute__((address_space(1))) void*)g,
        (__attribute__((address_space(3))) void*)l, 16, 0, 0);
}

// ---------------- CSR build ----------------

__global__ __launch_bounds__(256) void edge_count(const int* __restrict__ ei, int E, int n,
                                                  int* __restrict__ deg) {
    int e = blockIdx.x * blockDim.x + threadIdx.x;
    int Etot = E + n;
    if (e >= Etot) return;
    int dst = (e < E) ? ei[E + e] : (e - E);   // self-loop for e >= E
    atomicAdd(&deg[dst], 1);
}

__global__ __launch_bounds__(256) void scan_partials(const int* __restrict__ deg,
                                                     int* __restrict__ partial, int n) {
    __shared__ int red[256];
    int i0 = blockIdx.x * 1024 + threadIdx.x * 4;
    int s = 0;
#pragma unroll
    for (int r = 0; r < 4; ++r) s += (i0 + r < n) ? deg[i0 + r] : 0;
    red[threadIdx.x] = s;
    __syncthreads();
    for (int off = 128; off > 0; off >>= 1) {
        if (threadIdx.x < off) red[threadIdx.x] += red[threadIdx.x + off];
        __syncthreads();
    }
    if (threadIdx.x == 0) partial[blockIdx.x] = red[0];
}

__global__ __launch_bounds__(128) void scan_mid(int* __restrict__ partial, int nb,
                                                int* __restrict__ offs, int n) {
    __shared__ int s[128];
    int v = (threadIdx.x < nb) ? partial[threadIdx.x] : 0;
    s[threadIdx.x] = v;
    __syncthreads();
    for (int off = 1; off < 128; off <<= 1) {
        int t = (threadIdx.x >= off) ? s[threadIdx.x - off] : 0;
        __syncthreads();
        s[threadIdx.x] += t;
        __syncthreads();
    }
    if (threadIdx.x < nb) partial[threadIdx.x] = s[threadIdx.x] - v;   // exclusive
    if (threadIdx.x == nb - 1) offs[n] = s[threadIdx.x];               // total
}

__global__ __launch_bounds__(256) void scan_final(const int* __restrict__ deg,
                                                  const int* __restrict__ partial,
                                                  int* __restrict__ offs,
                                                  int* __restrict__ cursor, int n) {
    __shared__ int s[256];
    int i0 = blockIdx.x * 1024 + threadIdx.x * 4;
    int v[4];
    int sum = 0;
#pragma unroll
    for (int r = 0; r < 4; ++r) {
        v[r] = (i0 + r < n) ? deg[i0 + r] : 0;
        sum += v[r];
    }
    s[threadIdx.x] = sum;
    __syncthreads();
    for (int off = 1; off < 256; off <<= 1) {
        int t = (threadIdx.x >= off) ? s[threadIdx.x - off] : 0;
        __syncthreads();
        s[threadIdx.x] += t;
        __syncthreads();
    }
    int excl = s[threadIdx.x] - sum + partial[blockIdx.x];
#pragma unroll
    for (int r = 0; r < 4; ++r) {
        if (i0 + r < n) { offs[i0 + r] = excl; cursor[i0 + r] = excl; }
        excl += v[r];
    }
}

__global__ __launch_bounds__(256) void edge_fill(const int* __restrict__ ei, int E, int n,
                                                 int* __restrict__ cursor,
                                                 int* __restrict__ csr) {
    int e = blockIdx.x * blockDim.x + threadIdx.x;
    int Etot = E + n;
    if (e >= Etot) return;
    int src, dst;
    if (e < E) { src = ei[e]; dst = ei[E + e]; }
    else       { src = e - E; dst = e - E; }
    int pos = atomicAdd(&cursor[dst], 1);
    csr[pos] = src;
}

// -------- Pack W into MFMA-fragment-major hi/lo bf16 ----------------------

__global__ __launch_bounds__(256) void pack_frag(const float* __restrict__ W,
                                                 u16* __restrict__ Bhi,
                                                 u16* __restrict__ Blo, int N) {
    int CT = N / 16;
    int idx = blockIdx.x * blockDim.x + threadIdx.x;
    if (idx >= 8 * CT * 64) return;
    int lane = idx & 63;
    int ctkb = idx >> 6;
    int ct = ctkb % CT;
    int kb = ctkb / CT;
    int col = ct * 16 + (lane & 15);
    int k0 = kb * 32 + (lane >> 4) * 8;
#pragma unroll
    for (int j = 0; j < 8; ++j) {
        float w = W[(size_t)(k0 + j) * N + col];
        u16 hi = f2b(w);
        Bhi[(size_t)idx * 8 + j] = hi;
        Blo[(size_t)idx * 8 + j] = f2b(w - b2f(hi));
    }
}

// ------- Layer-1 linear (K=3) + fused scores; writes bf16 shadow only -----

__global__ __launch_bounds__(256) void linear1(const float* __restrict__ x,
                                               const float* __restrict__ W,
                                               const float* __restrict__ asrc,
                                               const float* __restrict__ adst,
                                               u16* __restrict__ Hb,
                                               float* __restrict__ ssrc,
                                               float* __restrict__ sdst, int n) {
    int node = blockIdx.x;
    if (node >= n) return;
    int c = threadIdx.x;
    int head = c >> 6, lane = c & 63;
    float x0 = x[node * 3 + 0], x1 = x[node * 3 + 1], x2 = x[node * 3 + 2];
    float v = fmaf(x0, W[c], fmaf(x1, W[256 + c], x2 * W[512 + c]));
    Hb[(size_t)node * 256 + c] = f2b(v);
    float va = v * asrc[c];
    float vb = v * adst[c];
#pragma unroll
    for (int o = 32; o > 0; o >>= 1) {
        va += __shfl_xor(va, o);
        vb += __shfl_xor(vb, o);
    }
    if (lane == 0) { ssrc[node * 4 + head] = va; sdst[node * 4 + head] = vb; }
}

// ------- Async 2-phase split-precision MFMA GEMM --------------------------
// out = A[n x 256] * W^T (NCOLS = CT*16). A pre-split hi/lo bf16 (producer-
// written, numerically identical to in-GEMM decomposition).
// D = Ahi*Whi + Alo*Whi + Ahi*Wlo (fp32 acc).
// B: double-buffered LDS via global_load_lds (fragment-major linear;
//    64 lanes read consecutive 16B chunks -> conflict-free ds_read_b128).
// A: direct global->VGPR bf16x8 loads with 1-deep register prefetch
//    (latency hidden under MFMA phase; barrier's vmcnt(0) is the drain).
// Fragments: A[m=lane&15][k=(lane>>4)*8+j]; D reg r -> row (l>>4)*4+r, col l&15.

template <int CT, int HEADS>
__global__ __launch_bounds__(256, 2) void gemm_async(const u16* __restrict__ Ahi,
                                                     const u16* __restrict__ Alo,
                                                     const u16* __restrict__ Bhi,
                                                     const u16* __restrict__ Blo,
                                                     const float* __restrict__ asrc,
                                                     const float* __restrict__ adst,
                                                     u16* __restrict__ Hb,
                                                     float* __restrict__ ssrc,
                                                     float* __restrict__ sdst, int n) {
    constexpr int BFRAG = CT * 64;          // B 16B-chunks per kb per array
    constexpr int BSZ = BFRAG * 8;          // u16 per B array per kb slice
    __shared__ __align__(16) u16 lds[2][2 * BSZ];

    int t = threadIdx.x;
    int w = t >> 6, l = t & 63;
    int m0 = blockIdx.x * 64 + w * 16;      // row-split: wave owns 16 rows
    int lm = l & 15, q = l >> 4;

    int arow = min(m0 + lm, n - 1);         // clamp OOB rows (stores guarded)
    const u16* aH = Ahi + (size_t)arow * 256 + q * 8;
    const u16* aL = Alo + (size_t)arow * 256 + q * 8;

    floatx4 acc[CT] = {};

    auto stageB = [&](int buf, int kb) {
        u16* L = &lds[buf][0];
        constexpr int BROUNDS = (BFRAG + 255) / 256;
#pragma unroll
        for (int r = 0; r < BROUNDS; ++r) {
            int u = r * 256 + t;
            if (BFRAG >= (r + 1) * 256 || u < BFRAG) {
                size_t off = ((size_t)kb * BFRAG + (size_t)u) * 8;
                u16* Lb = L + (size_t)(r * 256 + w * 64) * 8;   // wave-uniform
                load16(Bhi + off, Lb);
                load16(Blo + off, Lb + BSZ);
            }
        }
    };

    stageB(0, 0);
    bf16x8 ahi = *(const bf16x8*)aH;        // kb=0 A fragments
    bf16x8 alo = *(const bf16x8*)aL;
    __syncthreads();    // implicit vmcnt(0): buf0 + A loads done

    for (int kb = 0; kb < 8; ++kb) {
        int cur = kb & 1;
        bf16x8 nhi = ahi, nlo = alo;
        if (kb < 7) {
            stageB(cur ^ 1, kb + 1);                      // async B prefetch
            nhi = *(const bf16x8*)(aH + (kb + 1) * 32);   // A reg prefetch
            nlo = *(const bf16x8*)(aL + (kb + 1) * 32);
        }
        const u16* L = &lds[cur][0];
#pragma unroll
        for (int ct = 0; ct < CT; ++ct) {
            bf16x8 bhi = *(const bf16x8*)&L[(ct * 64 + l) * 8];
            bf16x8 blo = *(const bf16x8*)&L[BSZ + (ct * 64 + l) * 8];
            acc[ct] = __builtin_amdgcn_mfma_f32_16x16x32_bf16(ahi, bhi, acc[ct], 0, 0, 0);
            acc[ct] = __builtin_amdgcn_mfma_f32_16x16x32_bf16(alo, bhi, acc[ct], 0, 0, 0);
            acc[ct] = __builtin_amdgcn_mfma_f32_16x16x32_bf16(ahi, blo, acc[ct], 0, 0, 0);
        }
        __syncthreads();   // drains next-tile stage + A prefetch (vmcnt 0)
        ahi = nhi; alo = nlo;
    }

    // ---- bf16 shadow store ----
#pragma unroll
    for (int ct = 0; ct < CT; ++ct) {
#pragma unroll
        for (int r = 0; r < 4; ++r) {
            int row = m0 + q * 4 + r;
            if (row < n)
                Hb[(size_t)row * (CT * 16) + ct * 16 + lm] = f2b(acc[ct][r]);
        }
    }
    // ---- fused scores: per-row, per-head dot with asrc/adst -------------
    constexpr int CPH = CT / HEADS;          // col-tiles per head
    float ps[4][HEADS] = {}, pd[4][HEADS] = {};
#pragma unroll
    for (int h = 0; h < HEADS; ++h) {
#pragma unroll
        for (int j = 0; j < CPH; ++j) {
            int ct = h * CPH + j;
            float a_s = asrc[ct * 16 + lm];
            float a_d = adst[ct * 16 + lm];
#pragma unroll
            for (int r = 0; r < 4; ++r) {
                ps[r][h] = fmaf(acc[ct][r], a_s, ps[r][h]);
                pd[r][h] = fmaf(acc[ct][r], a_d, pd[r][h]);
            }
        }
    }
#pragma unroll
    for (int r = 0; r < 4; ++r)
#pragma unroll
        for (int h = 0; h < HEADS; ++h)
#pragma unroll
            for (int o = 1; o < 16; o <<= 1) {
                ps[r][h] += __shfl_xor(ps[r][h], o);
                pd[r][h] += __shfl_xor(pd[r][h], o);
            }
#pragma unroll
    for (int h = 0; h < HEADS; ++h) {
        if (lm == h) {
#pragma unroll
            for (int r = 0; r < 4; ++r) {
                int row = m0 + q * 4 + r;
                if (row < n) {
                    ssrc[row * HEADS + h] = ps[r][h];
                    sdst[row * HEADS + h] = pd[r][h];
                }
            }
        }
    }
}

// ---------------- Merged 4-head aggregation (layers 1 & 2) ----------------
// One wave per dst node. Lane l: fp32 float4 acc (channels l*4..+3, head
// hA=l>>4); softmax state head hB=l&3, edge slot eL=l>>2.
// R11: fast path for deg<=16 -- csr read once, ssrc + all 16 value-row
// gathers issued BEFORE the softmax shuffle chain (loads in flight under
// the reductions); exact softmax, single consume pass. Slow path (deg>16):
// phase A online (m,l), phase B hoisted 16-deep gather per chunk.
// Epilogue writes hi/lo bf16 decomposition of relu(acc/l + bias).

__global__ __launch_bounds__(256) void gat_aggregate_m4(const u16* __restrict__ Hb,
                                                        const float* __restrict__ ssrc,
                                                        const float* __restrict__ sdst,
                                                        const int* __restrict__ offs,
                                                        const int* __restrict__ csr,
                                                        const float* __restrict__ bias,
                                                        u16* __restrict__ outHi,
                                                        u16* __restrict__ outLo, int n) {
    int node = blockIdx.x * 4 + (threadIdx.x >> 6);
    int lane = threadIdx.x & 63;
    if (node >= n) return;
    const int hB = lane & 3;
    const int eL = lane >> 2;
    const int hA = lane >> 4;
    int beg = offs[node], end = offs[node + 1];
    int deg = end - beg;
    float sd = sdst[node * 4 + hB];
    float4 acc = make_float4(0.f, 0.f, 0.f, 0.f);
    float l;

    if (deg <= 16) {
        // ---------- fast path: one chunk, issue-early gathers ----------
        bool valid = (eL < deg);
        int sj = valid ? csr[beg + eL] : 0;
        float sv = valid ? ssrc[sj * 4 + hB] : 0.f;   // issued first (vmcnt order)
        ushort4 hv[16];
#pragma unroll
        for (int i = 0; i < 16; ++i) {
            if (i < deg) {                            // wave-uniform guard
                int s = __shfl(sj, i * 4);
                hv[i] = *(const ushort4*)&Hb[(size_t)s * 256 + lane * 4];
            }
        }
        float logit = -INFINITY;
        if (valid) {
            float xv = sv + sd;
            logit = (xv > 0.f) ? xv : NEG_SLOPE * xv;
        }
        float cm = logit;
        cm = fmaxf(cm, __shfl_xor(cm, 4));
        cm = fmaxf(cm, __shfl_xor(cm, 8));
        cm = fmaxf(cm, __shfl_xor(cm, 16));
        cm = fmaxf(cm, __shfl_xor(cm, 32));
        float ex = valid ? __expf(logit - cm) : 0.f;
        l = ex;
        l += __shfl_xor(l, 4);
        l += __shfl_xor(l, 8);
        l += __shfl_xor(l, 16);
        l += __shfl_xor(l, 32);
#pragma unroll
        for (int i = 0; i < 16; ++i) {
            if (i < deg) {
                float a = __shfl(ex, i * 4 + hA);
                acc.x = fmaf(a, b2f(hv[i].x), acc.x);
                acc.y = fmaf(a, b2f(hv[i].y), acc.y);
                acc.z = fmaf(a, b2f(hv[i].z), acc.z);
                acc.w = fmaf(a, b2f(hv[i].w), acc.w);
            }
        }
    } else {
        // ---------- slow path: phase A stats, phase B hoisted gather ----
        float m = -INFINITY;
        l = 0.f;
        for (int base = beg; base < end; base += 16) {
            int j = base + eL;
            bool valid = (j < end);
            int sj = valid ? csr[j] : 0;
            float logit = -INFINITY;
            if (valid) {
                float xv = ssrc[sj * 4 + hB] + sd;
                logit = (xv > 0.f) ? xv : NEG_SLOPE * xv;
            }
            float cm = logit;
            cm = fmaxf(cm, __shfl_xor(cm, 4));
            cm = fmaxf(cm, __shfl_xor(cm, 8));
            cm = fmaxf(cm, __shfl_xor(cm, 16));
            cm = fmaxf(cm, __shfl_xor(cm, 32));
            float nm = fmaxf(m, cm);
            float ex = valid ? __expf(logit - nm) : 0.f;
            float es = ex;
            es += __shfl_xor(es, 4);
            es += __shfl_xor(es, 8);
            es += __shfl_xor(es, 16);
            es += __shfl_xor(es, 32);
            l = l * __expf(m - nm) + es;
            m = nm;
        }
        for (int base = beg; base < end; base += 16) {
            int j = base + eL;
            bool valid = (j < end);
            int sj = valid ? csr[j] : 0;
            int cnt = min(16, end - base);
            float sv = valid ? ssrc[sj * 4 + hB] : 0.f;
            ushort4 hv[16];
#pragma unroll
            for (int i = 0; i < 16; ++i) {
                if (i < cnt) {
                    int s = __shfl(sj, i * 4);
                    hv[i] = *(const ushort4*)&Hb[(size_t)s * 256 + lane * 4];
                }
            }
            float logit = -INFINITY;
            if (valid) {
                float xv = sv + sd;
                logit = (xv > 0.f) ? xv : NEG_SLOPE * xv;
            }
            float ex = valid ? __expf(logit - m) : 0.f;   // final m: no rescale
#pragma unroll
            for (int i = 0; i < 16; ++i) {
                if (i < cnt) {
                    float a = __shfl(ex, i * 4 + hA);
                    acc.x = fmaf(a, b2f(hv[i].x), acc.x);
                    acc.y = fmaf(a, b2f(hv[i].y), acc.y);
                    acc.z = fmaf(a, b2f(hv[i].z), acc.z);
                    acc.w = fmaf(a, b2f(hv[i].w), acc.w);
                }
            }
        }
    }

    float lf = __shfl(l, hA);
    float inv = 1.f / lf;
    const float4 bv = *(const float4*)&bias[lane * 4];
    float4 o;
    o.x = fmaxf(fmaf(acc.x, inv, bv.x), 0.f);   // relu (layers 1 & 2)
    o.y = fmaxf(fmaf(acc.y, inv, bv.y), 0.f);
    o.z = fmaxf(fmaf(acc.z, inv, bv.z), 0.f);
    o.w = fmaxf(fmaf(acc.w, inv, bv.w), 0.f);
    ushort4 h4, l4;
    h4.x = f2b(o.x); l4.x = f2b(o.x - b2f(h4.x));
    h4.y = f2b(o.y); l4.y = f2b(o.y - b2f(h4.y));
    h4.z = f2b(o.z); l4.z = f2b(o.z - b2f(h4.z));
    h4.w = f2b(o.w); l4.w = f2b(o.w - b2f(h4.w));
    *(ushort4*)&outHi[(size_t)node * 256 + lane * 4] = h4;
    *(ushort4*)&outLo[(size_t)node * 256 + lane * 4] = l4;
}

// ---------------- Single-head aggregation (layer 3, C=32, no relu) --------

__global__ __launch_bounds__(256) void gat_aggregate_h1(const u16* __restrict__ Hb,
                                                        const float* __restrict__ ssrc,
                                                        const float* __restrict__ sdst,
                                                        const int* __restrict__ offs,
                                                        const int* __restrict__ csr,
                                                        const float* __restrict__ bias,
                                                        float* __restrict__ out, int n) {
    int node = blockIdx.x * 4 + (threadIdx.x >> 6);
    int lane = threadIdx.x & 63;
    if (node >= n) return;
    int beg = offs[node], end = offs[node + 1];
    float sd = sdst[node];
    float m = -INFINITY, l = 0.f, acc = 0.f;

    for (int base = beg; base < end; base += 64) {
        int j = base + lane;
        bool valid = (j < end);
        int sj = valid ? csr[j] : 0;
        float logit = -INFINITY;
        if (valid) {
            float xv = ssrc[sj] + sd;
            logit = (xv > 0.f) ? xv : NEG_SLOPE * xv;
        }
        float cm = logit;
#pragma unroll
        for (int o = 32; o > 0; o >>= 1) cm = fmaxf(cm, __shfl_xor(cm, o));
        float nm = fmaxf(m, cm);
        float scale = __expf(m - nm);
        float ex = valid ? __expf(logit - nm) : 0.f;
        float es = ex;
#pragma unroll
        for (int o = 32; o > 0; o >>= 1) es += __shfl_xor(es, o);
        l = l * scale + es;
        m = nm;
        acc *= scale;
        int cnt = min(64, end - base);
        for (int t = 0; t < cnt; t += 4) {
#pragma unroll
            for (int u = 0; u < 4; ++u) {
                float a = __shfl(ex, t + u);
                int s = __shfl(sj, t + u);
                if (lane < 32) acc = fmaf(a, b2f(Hb[(size_t)s * 32 + lane]), acc);
            }
        }
    }
    if (lane < 32) out[(size_t)node * 32 + lane] = acc / l + bias[lane];
}

// ---------------- Launch ----------------

extern "C" void kernel_launch(void* const* d_in, const int* in_sizes, int n_in,
                              void* d_out, int out_size, void* d_ws, size_t ws_size,
                              hipStream_t stream) {
    const float* x   = (const float*)d_in[0];
    const int*   ei  = (const int*)d_in[1];
    const float* W1  = (const float*)d_in[2];
    const float* as1 = (const float*)d_in[3];
    const float* ad1 = (const float*)d_in[4];
    const float* b1  = (const float*)d_in[5];
    const float* W2  = (const float*)d_in[6];
    const float* as2 = (const float*)d_in[7];
    const float* ad2 = (const float*)d_in[8];
    const float* b2  = (const float*)d_in[9];
    const float* W3  = (const float*)d_in[10];
    const float* as3 = (const float*)d_in[11];
    const float* ad3 = (const float*)d_in[12];
    const float* b3  = (const float*)d_in[13];
    float* out = (float*)d_out;

    const int n = in_sizes[0] / 3;     // 50000
    const int E = in_sizes[1] / 2;     // 400000
    const int Etot = E + n;            // with self-loops

    // workspace layout (~84 MB)
    char* ws = (char*)d_ws;
    u16* Fhi  = (u16*)ws;    ws += (size_t)n * 256 * sizeof(u16);     // 25.6 MB split hi
    u16* Flo  = (u16*)ws;    ws += (size_t)n * 256 * sizeof(u16);     // 25.6 MB split lo
    u16* Hb   = (u16*)ws;    ws += (size_t)n * 256 * sizeof(u16);     // 25.6 MB bf16 shadow
    u16* Hb3  = (u16*)ws;    ws += (size_t)n * 32 * sizeof(u16);      // 3.2 MB
    u16* B2h  = (u16*)ws;    ws += (size_t)8 * 16 * 64 * 8 * sizeof(u16);
    u16* B2l  = (u16*)ws;    ws += (size_t)8 * 16 * 64 * 8 * sizeof(u16);
    u16* B3h  = (u16*)ws;    ws += (size_t)8 * 2 * 64 * 8 * sizeof(u16);
    u16* B3l  = (u16*)ws;    ws += (size_t)8 * 2 * 64 * 8 * sizeof(u16);
    float* ssrc = (float*)ws;  ws += (size_t)n * 4 * sizeof(float);
    float* sdst = (float*)ws;  ws += (size_t)n * 4 * sizeof(float);
    int* deg    = (int*)ws;    ws += (size_t)n * sizeof(int);
    int* offs   = (int*)ws;    ws += (size_t)(n + 1) * sizeof(int) + 12;
    int* cursor = (int*)ws;    ws += (size_t)n * sizeof(int);
    int* partial = (int*)ws;   ws += (size_t)128 * sizeof(int);
    int* csr    = (int*)ws;    ws += (size_t)Etot * sizeof(int);   // keep csr LAST

    // ---- CSR build (by dst) ----
    hipMemsetAsync(deg, 0, (size_t)n * sizeof(int), stream);
    int eblocks = (Etot + 255) / 256;
    edge_count<<<eblocks, 256, 0, stream>>>(ei, E, n, deg);
    int sb = (n + 1023) / 1024;
    scan_partials<<<sb, 256, 0, stream>>>(deg, partial, n);
    scan_mid<<<1, 128, 0, stream>>>(partial, sb, offs, n);
    scan_final<<<sb, 256, 0, stream>>>(deg, partial, offs, cursor, n);
    edge_fill<<<eblocks, 256, 0, stream>>>(ei, E, n, cursor, csr);

    // ---- Weight prep (fragment-major hi/lo pack) ----
    pack_frag<<<(8 * 16 * 64 + 255) / 256, 256, 0, stream>>>(W2, B2h, B2l, 256);
    pack_frag<<<(8 * 2 * 64 + 255) / 256, 256, 0, stream>>>(W3, B3h, B3l, 32);

    int nb4 = (n + 3) / 4;
    int nb64 = (n + 63) / 64;

    // ---- Layer 1: 3 -> (4 x 64), concat, relu ----
    linear1<<<n, 256, 0, stream>>>(x, W1, as1, ad1, Hb, ssrc, sdst, n);
    gat_aggregate_m4<<<nb4, 256, 0, stream>>>(Hb, ssrc, sdst, offs, csr, b1, Fhi, Flo, n);

    // ---- Layer 2: 256 -> (4 x 64), concat, relu ----
    gemm_async<16, 4><<<nb64, 256, 0, stream>>>(Fhi, Flo, B2h, B2l, as2, ad2, Hb, ssrc, sdst, n);
    gat_aggregate_m4<<<nb4, 256, 0, stream>>>(Hb, ssrc, sdst, offs, csr, b2, Fhi, Flo, n);

    // ---- Layer 3: 256 -> (1 x 32), mean(=identity), no relu ----
    gemm_async<2, 1><<<nb64, 256, 0, stream>>>(Fhi, Flo, B3h, B3l, as3, ad3, Hb3, ssrc, sdst, n);
    gat_aggregate_h1<<<nb4, 256, 0, stream>>>(Hb3, ssrc, sdst, offs, csr, b3, out, n);
}

// Round 4
// 341.799 us; speedup vs baseline: 1.0569x; 1.0569x over previous
//
#include <hip/hip_runtime.h>
#include <math.h>

// =====================================================================
// 3-layer GAT (PyG GATConv) on MI355X.
// R12: dual-node interleaved aggregation.
//  - agg_m4: one wave processes TWO nodes; both nodes' csr+ssrc loads
//    issue before either softmax chain (independent chains overlap the
//    memory latency). Online softmax per node, R10-style 4-deep consume.
//  - gemm_async unchanged from R10 (B dbuf global_load_lds + A reg
//    prefetch). Producers write hi/lo bf16 F; values gathered bf16.
// =====================================================================

#define NEG_SLOPE 0.2f

typedef unsigned short u16;
typedef short bf16x8 __attribute__((ext_vector_type(8)));
typedef float floatx4 __attribute__((ext_vector_type(4)));

__device__ __forceinline__ float b2f(u16 u) {
    return __uint_as_float(((unsigned int)u) << 16);
}
__device__ __forceinline__ u16 f2b(float f) {
    unsigned int u = __float_as_uint(f);
    unsigned int r = (u + 0x7fffu + ((u >> 16) & 1u)) >> 16;   // RNE
    return (u16)r;
}

// async 16B global -> LDS (DMA, no VGPR round-trip). LDS dest must be
// wave-uniform base; HW adds lane*16. Global source is per-lane.
__device__ __forceinline__ void load16(const u16* g, u16* l) {
    __builtin_amdgcn_global_load_lds(
        (const __attribute__((address_space(1))) void*)g,
        (__attribute__((address_space(3))) void*)l, 16, 0, 0);
}

// ---------------- CSR build ----------------

__global__ __launch_bounds__(256) void edge_count(const int* __restrict__ ei, int E, int n,
                                                  int* __restrict__ deg) {
    int e = blockIdx.x * blockDim.x + threadIdx.x;
    int Etot = E + n;
    if (e >= Etot) return;
    int dst = (e < E) ? ei[E + e] : (e - E);   // self-loop for e >= E
    atomicAdd(&deg[dst], 1);
}

__global__ __launch_bounds__(256) void scan_partials(const int* __restrict__ deg,
                                                     int* __restrict__ partial, int n) {
    __shared__ int red[256];
    int i0 = blockIdx.x * 1024 + threadIdx.x * 4;
    int s = 0;
#pragma unroll
    for (int r = 0; r < 4; ++r) s += (i0 + r < n) ? deg[i0 + r] : 0;
    red[threadIdx.x] = s;
    __syncthreads();
    for (int off = 128; off > 0; off >>= 1) {
        if (threadIdx.x < off) red[threadIdx.x] += red[threadIdx.x + off];
        __syncthreads();
    }
    if (threadIdx.x == 0) partial[blockIdx.x] = red[0];
}

__global__ __launch_bounds__(128) void scan_mid(int* __restrict__ partial, int nb,
                                                int* __restrict__ offs, int n) {
    __shared__ int s[128];
    int v = (threadIdx.x < nb) ? partial[threadIdx.x] : 0;
    s[threadIdx.x] = v;
    __syncthreads();
    for (int off = 1; off < 128; off <<= 1) {
        int t = (threadIdx.x >= off) ? s[threadIdx.x - off] : 0;
        __syncthreads();
        s[threadIdx.x] += t;
        __syncthreads();
    }
    if (threadIdx.x < nb) partial[threadIdx.x] = s[threadIdx.x] - v;   // exclusive
    if (threadIdx.x == nb - 1) offs[n] = s[threadIdx.x];               // total
}

__global__ __launch_bounds__(256) void scan_final(const int* __restrict__ deg,
                                                  const int* __restrict__ partial,
                                                  int* __restrict__ offs,
                                                  int* __restrict__ cursor, int n) {
    __shared__ int s[256];
    int i0 = blockIdx.x * 1024 + threadIdx.x * 4;
    int v[4];
    int sum = 0;
#pragma unroll
    for (int r = 0; r < 4; ++r) {
        v[r] = (i0 + r < n) ? deg[i0 + r] : 0;
        sum += v[r];
    }
    s[threadIdx.x] = sum;
    __syncthreads();
    for (int off = 1; off < 256; off <<= 1) {
        int t = (threadIdx.x >= off) ? s[threadIdx.x - off] : 0;
        __syncthreads();
        s[threadIdx.x] += t;
        __syncthreads();
    }
    int excl = s[threadIdx.x] - sum + partial[blockIdx.x];
#pragma unroll
    for (int r = 0; r < 4; ++r) {
        if (i0 + r < n) { offs[i0 + r] = excl; cursor[i0 + r] = excl; }
        excl += v[r];
    }
}

__global__ __launch_bounds__(256) void edge_fill(const int* __restrict__ ei, int E, int n,
                                                 int* __restrict__ cursor,
                                                 int* __restrict__ csr) {
    int e = blockIdx.x * blockDim.x + threadIdx.x;
    int Etot = E + n;
    if (e >= Etot) return;
    int src, dst;
    if (e < E) { src = ei[e]; dst = ei[E + e]; }
    else       { src = e - E; dst = e - E; }
    int pos = atomicAdd(&cursor[dst], 1);
    csr[pos] = src;
}

// -------- Pack W into MFMA-fragment-major hi/lo bf16 ----------------------

__global__ __launch_bounds__(256) void pack_frag(const float* __restrict__ W,
                                                 u16* __restrict__ Bhi,
                                                 u16* __restrict__ Blo, int N) {
    int CT = N / 16;
    int idx = blockIdx.x * blockDim.x + threadIdx.x;
    if (idx >= 8 * CT * 64) return;
    int lane = idx & 63;
    int ctkb = idx >> 6;
    int ct = ctkb % CT;
    int kb = ctkb / CT;
    int col = ct * 16 + (lane & 15);
    int k0 = kb * 32 + (lane >> 4) * 8;
#pragma unroll
    for (int j = 0; j < 8; ++j) {
        float w = W[(size_t)(k0 + j) * N + col];
        u16 hi = f2b(w);
        Bhi[(size_t)idx * 8 + j] = hi;
        Blo[(size_t)idx * 8 + j] = f2b(w - b2f(hi));
    }
}

// ------- Layer-1 linear (K=3) + fused scores; writes bf16 shadow only -----

__global__ __launch_bounds__(256) void linear1(const float* __restrict__ x,
                                               const float* __restrict__ W,
                                               const float* __restrict__ asrc,
                                               const float* __restrict__ adst,
                                               u16* __restrict__ Hb,
                                               float* __restrict__ ssrc,
                                               float* __restrict__ sdst, int n) {
    int node = blockIdx.x;
    if (node >= n) return;
    int c = threadIdx.x;
    int head = c >> 6, lane = c & 63;
    float x0 = x[node * 3 + 0], x1 = x[node * 3 + 1], x2 = x[node * 3 + 2];
    float v = fmaf(x0, W[c], fmaf(x1, W[256 + c], x2 * W[512 + c]));
    Hb[(size_t)node * 256 + c] = f2b(v);
    float va = v * asrc[c];
    float vb = v * adst[c];
#pragma unroll
    for (int o = 32; o > 0; o >>= 1) {
        va += __shfl_xor(va, o);
        vb += __shfl_xor(vb, o);
    }
    if (lane == 0) { ssrc[node * 4 + head] = va; sdst[node * 4 + head] = vb; }
}

// ------- Async 2-phase split-precision MFMA GEMM --------------------------
// out = A[n x 256] * W^T (NCOLS = CT*16). A pre-split hi/lo bf16 (producer-
// written, numerically identical to in-GEMM decomposition).
// D = Ahi*Whi + Alo*Whi + Ahi*Wlo (fp32 acc).
// B: double-buffered LDS via global_load_lds (fragment-major linear;
//    64 lanes read consecutive 16B chunks -> conflict-free ds_read_b128).
// A: direct global->VGPR bf16x8 loads with 1-deep register prefetch
//    (latency hidden under MFMA phase; barrier's vmcnt(0) is the drain).
// Fragments: A[m=lane&15][k=(lane>>4)*8+j]; D reg r -> row (l>>4)*4+r, col l&15.

template <int CT, int HEADS>
__global__ __launch_bounds__(256, 2) void gemm_async(const u16* __restrict__ Ahi,
                                                     const u16* __restrict__ Alo,
                                                     const u16* __restrict__ Bhi,
                                                     const u16* __restrict__ Blo,
                                                     const float* __restrict__ asrc,
                                                     const float* __restrict__ adst,
                                                     u16* __restrict__ Hb,
                                                     float* __restrict__ ssrc,
                                                     float* __restrict__ sdst, int n) {
    constexpr int BFRAG = CT * 64;          // B 16B-chunks per kb per array
    constexpr int BSZ = BFRAG * 8;          // u16 per B array per kb slice
    __shared__ __align__(16) u16 lds[2][2 * BSZ];

    int t = threadIdx.x;
    int w = t >> 6, l = t & 63;
    int m0 = blockIdx.x * 64 + w * 16;      // row-split: wave owns 16 rows
    int lm = l & 15, q = l >> 4;

    int arow = min(m0 + lm, n - 1);         // clamp OOB rows (stores guarded)
    const u16* aH = Ahi + (size_t)arow * 256 + q * 8;
    const u16* aL = Alo + (size_t)arow * 256 + q * 8;

    floatx4 acc[CT] = {};

    auto stageB = [&](int buf, int kb) {
        u16* L = &lds[buf][0];
        constexpr int BROUNDS = (BFRAG + 255) / 256;
#pragma unroll
        for (int r = 0; r < BROUNDS; ++r) {
            int u = r * 256 + t;
            if (BFRAG >= (r + 1) * 256 || u < BFRAG) {
                size_t off = ((size_t)kb * BFRAG + (size_t)u) * 8;
                u16* Lb = L + (size_t)(r * 256 + w * 64) * 8;   // wave-uniform
                load16(Bhi + off, Lb);
                load16(Blo + off, Lb + BSZ);
            }
        }
    };

    stageB(0, 0);
    bf16x8 ahi = *(const bf16x8*)aH;        // kb=0 A fragments
    bf16x8 alo = *(const bf16x8*)aL;
    __syncthreads();    // implicit vmcnt(0): buf0 + A loads done

    for (int kb = 0; kb < 8; ++kb) {
        int cur = kb & 1;
        bf16x8 nhi = ahi, nlo = alo;
        if (kb < 7) {
            stageB(cur ^ 1, kb + 1);                      // async B prefetch
            nhi = *(const bf16x8*)(aH + (kb + 1) * 32);   // A reg prefetch
            nlo = *(const bf16x8*)(aL + (kb + 1) * 32);
        }
        const u16* L = &lds[cur][0];
#pragma unroll
        for (int ct = 0; ct < CT; ++ct) {
            bf16x8 bhi = *(const bf16x8*)&L[(ct * 64 + l) * 8];
            bf16x8 blo = *(const bf16x8*)&L[BSZ + (ct * 64 + l) * 8];
            acc[ct] = __builtin_amdgcn_mfma_f32_16x16x32_bf16(ahi, bhi, acc[ct], 0, 0, 0);
            acc[ct] = __builtin_amdgcn_mfma_f32_16x16x32_bf16(alo, bhi, acc[ct], 0, 0, 0);
            acc[ct] = __builtin_amdgcn_mfma_f32_16x16x32_bf16(ahi, blo, acc[ct], 0, 0, 0);
        }
        __syncthreads();   // drains next-tile stage + A prefetch (vmcnt 0)
        ahi = nhi; alo = nlo;
    }

    // ---- bf16 shadow store ----
#pragma unroll
    for (int ct = 0; ct < CT; ++ct) {
#pragma unroll
        for (int r = 0; r < 4; ++r) {
            int row = m0 + q * 4 + r;
            if (row < n)
                Hb[(size_t)row * (CT * 16) + ct * 16 + lm] = f2b(acc[ct][r]);
        }
    }
    // ---- fused scores: per-row, per-head dot with asrc/adst -------------
    constexpr int CPH = CT / HEADS;          // col-tiles per head
    float ps[4][HEADS] = {}, pd[4][HEADS] = {};
#pragma unroll
    for (int h = 0; h < HEADS; ++h) {
#pragma unroll
        for (int j = 0; j < CPH; ++j) {
            int ct = h * CPH + j;
            float a_s = asrc[ct * 16 + lm];
            float a_d = adst[ct * 16 + lm];
#pragma unroll
            for (int r = 0; r < 4; ++r) {
                ps[r][h] = fmaf(acc[ct][r], a_s, ps[r][h]);
                pd[r][h] = fmaf(acc[ct][r], a_d, pd[r][h]);
            }
        }
    }
#pragma unroll
    for (int r = 0; r < 4; ++r)
#pragma unroll
        for (int h = 0; h < HEADS; ++h)
#pragma unroll
            for (int o = 1; o < 16; o <<= 1) {
                ps[r][h] += __shfl_xor(ps[r][h], o);
                pd[r][h] += __shfl_xor(pd[r][h], o);
            }
#pragma unroll
    for (int h = 0; h < HEADS; ++h) {
        if (lm == h) {
#pragma unroll
            for (int r = 0; r < 4; ++r) {
                int row = m0 + q * 4 + r;
                if (row < n) {
                    ssrc[row * HEADS + h] = ps[r][h];
                    sdst[row * HEADS + h] = pd[r][h];
                }
            }
        }
    }
}

// ---------------- Merged 4-head aggregation (layers 1 & 2) ----------------
// R12: one wave per TWO dst nodes (A,B). Both nodes' csr + ssrc gathers
// issue before either softmax chain -> independent latency chains overlap.
// Lane l: fp32 float4 acc (channels l*4..+3, head hA=l>>4); softmax state
// head hB=l&3, edge slot eL=l>>2. Online softmax per node (R10 structure).
// Epilogue writes hi/lo bf16 decomposition of relu(acc/l + bias).

__global__ __launch_bounds__(256) void gat_aggregate_m4(const u16* __restrict__ Hb,
                                                        const float* __restrict__ ssrc,
                                                        const float* __restrict__ sdst,
                                                        const int* __restrict__ offs,
                                                        const int* __restrict__ csr,
                                                        const float* __restrict__ bias,
                                                        u16* __restrict__ outHi,
                                                        u16* __restrict__ outLo, int n) {
    int pair = blockIdx.x * 4 + (threadIdx.x >> 6);
    int nodeA = pair * 2;
    int nodeB = pair * 2 + 1;
    if (nodeA >= n) return;
    bool hasB = (nodeB < n);
    int lane = threadIdx.x & 63;
    const int hB = lane & 3;
    const int eL = lane >> 2;
    const int hA = lane >> 4;

    int begA = offs[nodeA], endA = offs[nodeA + 1];
    int begB = hasB ? offs[nodeB] : 0;
    int endB = hasB ? offs[nodeB + 1] : 0;
    float sdA = sdst[nodeA * 4 + hB];
    float sdB = hasB ? sdst[nodeB * 4 + hB] : 0.f;

    float mA = -INFINITY, lA = 0.f;
    float mB = -INFINITY, lB = 0.f;
    float4 accA = make_float4(0.f, 0.f, 0.f, 0.f);
    float4 accB = make_float4(0.f, 0.f, 0.f, 0.f);

    int baseA = begA, baseB = begB;
    while (baseA < endA || baseB < endB) {
        bool doA = baseA < endA;
        bool doB = baseB < endB;
        // ---- issue both nodes' index + logit gathers up front ----
        bool vA = doA && (baseA + eL < endA);
        bool vB = doB && (baseB + eL < endB);
        int sjA = vA ? csr[baseA + eL] : 0;
        int sjB = vB ? csr[baseB + eL] : 0;
        float svA = vA ? ssrc[sjA * 4 + hB] : 0.f;
        float svB = vB ? ssrc[sjB * 4 + hB] : 0.f;

        // ---- softmax chain A (independent of B's -> ILP) ----
        float exA = 0.f, scaleA = 1.f;
        if (doA) {
            float logit = -INFINITY;
            if (vA) {
                float xv = svA + sdA;
                logit = (xv > 0.f) ? xv : NEG_SLOPE * xv;
            }
            float cm = logit;
            cm = fmaxf(cm, __shfl_xor(cm, 4));
            cm = fmaxf(cm, __shfl_xor(cm, 8));
            cm = fmaxf(cm, __shfl_xor(cm, 16));
            cm = fmaxf(cm, __shfl_xor(cm, 32));
            float nm = fmaxf(mA, cm);
            scaleA = __expf(mA - nm);
            exA = vA ? __expf(logit - nm) : 0.f;
            float es = exA;
            es += __shfl_xor(es, 4);
            es += __shfl_xor(es, 8);
            es += __shfl_xor(es, 16);
            es += __shfl_xor(es, 32);
            lA = lA * scaleA + es;
            mA = nm;
        }
        // ---- softmax chain B ----
        float exB = 0.f, scaleB = 1.f;
        if (doB) {
            float logit = -INFINITY;
            if (vB) {
                float xv = svB + sdB;
                logit = (xv > 0.f) ? xv : NEG_SLOPE * xv;
            }
            float cm = logit;
            cm = fmaxf(cm, __shfl_xor(cm, 4));
            cm = fmaxf(cm, __shfl_xor(cm, 8));
            cm = fmaxf(cm, __shfl_xor(cm, 16));
            cm = fmaxf(cm, __shfl_xor(cm, 32));
            float nm = fmaxf(mB, cm);
            scaleB = __expf(mB - nm);
            exB = vB ? __expf(logit - nm) : 0.f;
            float es = exB;
            es += __shfl_xor(es, 4);
            es += __shfl_xor(es, 8);
            es += __shfl_xor(es, 16);
            es += __shfl_xor(es, 32);
            lB = lB * scaleB + es;
            mB = nm;
        }

        // ---- consume A ----
        if (doA) {
            float sA = __shfl(scaleA, hA);
            accA.x *= sA; accA.y *= sA; accA.z *= sA; accA.w *= sA;
            int cnt = min(16, endA - baseA);
            for (int t = 0; t < cnt; t += 4) {
#pragma unroll
                for (int u = 0; u < 4; ++u) {
                    int tt = t + u;
                    float a = __shfl(exA, tt * 4 + hA);   // 0 for invalid edges
                    int s = __shfl(sjA, tt * 4);          // 0 for invalid (safe)
                    ushort4 hv = *(const ushort4*)&Hb[(size_t)s * 256 + lane * 4];
                    accA.x = fmaf(a, b2f(hv.x), accA.x);
                    accA.y = fmaf(a, b2f(hv.y), accA.y);
                    accA.z = fmaf(a, b2f(hv.z), accA.z);
                    accA.w = fmaf(a, b2f(hv.w), accA.w);
                }
            }
            baseA += 16;
        }
        // ---- consume B ----
        if (doB) {
            float sB = __shfl(scaleB, hA);
            accB.x *= sB; accB.y *= sB; accB.z *= sB; accB.w *= sB;
            int cnt = min(16, endB - baseB);
            for (int t = 0; t < cnt; t += 4) {
#pragma unroll
                for (int u = 0; u < 4; ++u) {
                    int tt = t + u;
                    float a = __shfl(exB, tt * 4 + hA);
                    int s = __shfl(sjB, tt * 4);
                    ushort4 hv = *(const ushort4*)&Hb[(size_t)s * 256 + lane * 4];
                    accB.x = fmaf(a, b2f(hv.x), accB.x);
                    accB.y = fmaf(a, b2f(hv.y), accB.y);
                    accB.z = fmaf(a, b2f(hv.z), accB.z);
                    accB.w = fmaf(a, b2f(hv.w), accB.w);
                }
            }
            baseB += 16;
        }
    }

    const float4 bv = *(const float4*)&bias[lane * 4];
    {
        float lf = __shfl(lA, hA);
        float inv = 1.f / lf;
        float4 o;
        o.x = fmaxf(fmaf(accA.x, inv, bv.x), 0.f);   // relu (layers 1 & 2)
        o.y = fmaxf(fmaf(accA.y, inv, bv.y), 0.f);
        o.z = fmaxf(fmaf(accA.z, inv, bv.z), 0.f);
        o.w = fmaxf(fmaf(accA.w, inv, bv.w), 0.f);
        ushort4 h4, l4;
        h4.x = f2b(o.x); l4.x = f2b(o.x - b2f(h4.x));
        h4.y = f2b(o.y); l4.y = f2b(o.y - b2f(h4.y));
        h4.z = f2b(o.z); l4.z = f2b(o.z - b2f(h4.z));
        h4.w = f2b(o.w); l4.w = f2b(o.w - b2f(h4.w));
        *(ushort4*)&outHi[(size_t)nodeA * 256 + lane * 4] = h4;
        *(ushort4*)&outLo[(size_t)nodeA * 256 + lane * 4] = l4;
    }
    if (hasB) {
        float lf = __shfl(lB, hA);
        float inv = 1.f / lf;
        float4 o;
        o.x = fmaxf(fmaf(accB.x, inv, bv.x), 0.f);
        o.y = fmaxf(fmaf(accB.y, inv, bv.y), 0.f);
        o.z = fmaxf(fmaf(accB.z, inv, bv.z), 0.f);
        o.w = fmaxf(fmaf(accB.w, inv, bv.w), 0.f);
        ushort4 h4, l4;
        h4.x = f2b(o.x); l4.x = f2b(o.x - b2f(h4.x));
        h4.y = f2b(o.y); l4.y = f2b(o.y - b2f(h4.y));
        h4.z = f2b(o.z); l4.z = f2b(o.z - b2f(h4.z));
        h4.w = f2b(o.w); l4.w = f2b(o.w - b2f(h4.w));
        *(ushort4*)&outHi[(size_t)nodeB * 256 + lane * 4] = h4;
        *(ushort4*)&outLo[(size_t)nodeB * 256 + lane * 4] = l4;
    }
}

// ---------------- Single-head aggregation (layer 3, C=32, no relu) --------

__global__ __launch_bounds__(256) void gat_aggregate_h1(const u16* __restrict__ Hb,
                                                        const float* __restrict__ ssrc,
                                                        const float* __restrict__ sdst,
                                                        const int* __restrict__ offs,
                                                        const int* __restrict__ csr,
                                                        const float* __restrict__ bias,
                                                        float* __restrict__ out, int n) {
    int node = blockIdx.x * 4 + (threadIdx.x >> 6);
    int lane = threadIdx.x & 63;
    if (node >= n) return;
    int beg = offs[node], end = offs[node + 1];
    float sd = sdst[node];
    float m = -INFINITY, l = 0.f, acc = 0.f;

    for (int base = beg; base < end; base += 64) {
        int j = base + lane;
        bool valid = (j < end);
        int sj = valid ? csr[j] : 0;
        float logit = -INFINITY;
        if (valid) {
            float xv = ssrc[sj] + sd;
            logit = (xv > 0.f) ? xv : NEG_SLOPE * xv;
        }
        float cm = logit;
#pragma unroll
        for (int o = 32; o > 0; o >>= 1) cm = fmaxf(cm, __shfl_xor(cm, o));
        float nm = fmaxf(m, cm);
        float scale = __expf(m - nm);
        float ex = valid ? __expf(logit - nm) : 0.f;
        float es = ex;
#pragma unroll
        for (int o = 32; o > 0; o >>= 1) es += __shfl_xor(es, o);
        l = l * scale + es;
        m = nm;
        acc *= scale;
        int cnt = min(64, end - base);
        for (int t = 0; t < cnt; t += 4) {
#pragma unroll
            for (int u = 0; u < 4; ++u) {
                float a = __shfl(ex, t + u);
                int s = __shfl(sj, t + u);
                if (lane < 32) acc = fmaf(a, b2f(Hb[(size_t)s * 32 + lane]), acc);
            }
        }
    }
    if (lane < 32) out[(size_t)node * 32 + lane] = acc / l + bias[lane];
}

// ---------------- Launch ----------------

extern "C" void kernel_launch(void* const* d_in, const int* in_sizes, int n_in,
                              void* d_out, int out_size, void* d_ws, size_t ws_size,
                              hipStream_t stream) {
    const float* x   = (const float*)d_in[0];
    const int*   ei  = (const int*)d_in[1];
    const float* W1  = (const float*)d_in[2];
    const float* as1 = (const float*)d_in[3];
    const float* ad1 = (const float*)d_in[4];
    const float* b1  = (const float*)d_in[5];
    const float* W2  = (const float*)d_in[6];
    const float* as2 = (const float*)d_in[7];
    const float* ad2 = (const float*)d_in[8];
    const float* b2  = (const float*)d_in[9];
    const float* W3  = (const float*)d_in[10];
    const float* as3 = (const float*)d_in[11];
    const float* ad3 = (const float*)d_in[12];
    const float* b3  = (const float*)d_in[13];
    float* out = (float*)d_out;

    const int n = in_sizes[0] / 3;     // 50000
    const int E = in_sizes[1] / 2;     // 400000
    const int Etot = E + n;            // with self-loops

    // workspace layout (~84 MB)
    char* ws = (char*)d_ws;
    u16* Fhi  = (u16*)ws;    ws += (size_t)n * 256 * sizeof(u16);     // 25.6 MB split hi
    u16* Flo  = (u16*)ws;    ws += (size_t)n * 256 * sizeof(u16);     // 25.6 MB split lo
    u16* Hb   = (u16*)ws;    ws += (size_t)n * 256 * sizeof(u16);     // 25.6 MB bf16 shadow
    u16* Hb3  = (u16*)ws;    ws += (size_t)n * 32 * sizeof(u16);      // 3.2 MB
    u16* B2h  = (u16*)ws;    ws += (size_t)8 * 16 * 64 * 8 * sizeof(u16);
    u16* B2l  = (u16*)ws;    ws += (size_t)8 * 16 * 64 * 8 * sizeof(u16);
    u16* B3h  = (u16*)ws;    ws += (size_t)8 * 2 * 64 * 8 * sizeof(u16);
    u16* B3l  = (u16*)ws;    ws += (size_t)8 * 2 * 64 * 8 * sizeof(u16);
    float* ssrc = (float*)ws;  ws += (size_t)n * 4 * sizeof(float);
    float* sdst = (float*)ws;  ws += (size_t)n * 4 * sizeof(float);
    int* deg    = (int*)ws;    ws += (size_t)n * sizeof(int);
    int* offs   = (int*)ws;    ws += (size_t)(n + 1) * sizeof(int) + 12;
    int* cursor = (int*)ws;    ws += (size_t)n * sizeof(int);
    int* partial = (int*)ws;   ws += (size_t)128 * sizeof(int);
    int* csr    = (int*)ws;    ws += (size_t)Etot * sizeof(int);   // keep csr LAST

    // ---- CSR build (by dst) ----
    hipMemsetAsync(deg, 0, (size_t)n * sizeof(int), stream);
    int eblocks = (Etot + 255) / 256;
    edge_count<<<eblocks, 256, 0, stream>>>(ei, E, n, deg);
    int sb = (n + 1023) / 1024;
    scan_partials<<<sb, 256, 0, stream>>>(deg, partial, n);
    scan_mid<<<1, 128, 0, stream>>>(partial, sb, offs, n);
    scan_final<<<sb, 256, 0, stream>>>(deg, partial, offs, cursor, n);
    edge_fill<<<eblocks, 256, 0, stream>>>(ei, E, n, cursor, csr);

    // ---- Weight prep (fragment-major hi/lo pack) ----
    pack_frag<<<(8 * 16 * 64 + 255) / 256, 256, 0, stream>>>(W2, B2h, B2l, 256);
    pack_frag<<<(8 * 2 * 64 + 255) / 256, 256, 0, stream>>>(W3, B3h, B3l, 32);

    int nb8 = (n + 7) / 8;             // agg_m4: 2 nodes/wave, 4 waves/block
    int nb4 = (n + 3) / 4;
    int nb64 = (n + 63) / 64;

    // ---- Layer 1: 3 -> (4 x 64), concat, relu ----
    linear1<<<n, 256, 0, stream>>>(x, W1, as1, ad1, Hb, ssrc, sdst, n);
    gat_aggregate_m4<<<nb8, 256, 0, stream>>>(Hb, ssrc, sdst, offs, csr, b1, Fhi, Flo, n);

    // ---- Layer 2: 256 -> (4 x 64), concat, relu ----
    gemm_async<16, 4><<<nb64, 256, 0, stream>>>(Fhi, Flo, B2h, B2l, as2, ad2, Hb, ssrc, sdst, n);
    gat_aggregate_m4<<<nb8, 256, 0, stream>>>(Hb, ssrc, sdst, offs, csr, b2, Fhi, Flo, n);

    // ---- Layer 3: 256 -> (1 x 32), mean(=identity), no relu ----
    gemm_async<2, 1><<<nb64, 256, 0, stream>>>(Fhi, Flo, B3h, B3l, as3, ad3, Hb3, ssrc, sdst, n);
    gat_aggregate_h1<<<nb4, 256, 0, stream>>>(Hb3, ssrc, sdst, offs, csr, b3, out, n);
}

// Round 5
// 330.778 us; speedup vs baseline: 1.0921x; 1.0333x over previous
//
#include <hip/hip_runtime.h>
#include <math.h>

// =====================================================================
// 3-layer GAT (PyG GATConv) on MI355X.
// R13: BM=128 8-wave GEMM (B-staging amortized 2x, no dispatch tail);
//      aggregation reverted to the known-good R10 single-node form.
//  - gemm_async: 512 thr / 8 waves, each wave owns 16 rows; B dbuf via
//    global_load_lds (linear fragment-major, conflict-free); A hi/lo
//    direct global->VGPR with 1-deep prefetch. 391 blocks, 2/CU.
//  - agg_m4: R10 structure (wave/node, online softmax, 4-deep consume),
//    hi/lo bf16 epilogue for the downstream split-precision GEMM.
// =====================================================================

#define NEG_SLOPE 0.2f

typedef unsigned short u16;
typedef short bf16x8 __attribute__((ext_vector_type(8)));
typedef float floatx4 __attribute__((ext_vector_type(4)));

__device__ __forceinline__ float b2f(u16 u) {
    return __uint_as_float(((unsigned int)u) << 16);
}
__device__ __forceinline__ u16 f2b(float f) {
    unsigned int u = __float_as_uint(f);
    unsigned int r = (u + 0x7fffu + ((u >> 16) & 1u)) >> 16;   // RNE
    return (u16)r;
}

// async 16B global -> LDS (DMA, no VGPR round-trip). LDS dest must be
// wave-uniform base; HW adds lane*16. Global source is per-lane.
__device__ __forceinline__ void load16(const u16* g, u16* l) {
    __builtin_amdgcn_global_load_lds(
        (const __attribute__((address_space(1))) void*)g,
        (__attribute__((address_space(3))) void*)l, 16, 0, 0);
}

// ---------------- CSR build ----------------

__global__ __launch_bounds__(256) void edge_count(const int* __restrict__ ei, int E, int n,
                                                  int* __restrict__ deg) {
    int e = blockIdx.x * blockDim.x + threadIdx.x;
    int Etot = E + n;
    if (e >= Etot) return;
    int dst = (e < E) ? ei[E + e] : (e - E);   // self-loop for e >= E
    atomicAdd(&deg[dst], 1);
}

__global__ __launch_bounds__(256) void scan_partials(const int* __restrict__ deg,
                                                     int* __restrict__ partial, int n) {
    __shared__ int red[256];
    int i0 = blockIdx.x * 1024 + threadIdx.x * 4;
    int s = 0;
#pragma unroll
    for (int r = 0; r < 4; ++r) s += (i0 + r < n) ? deg[i0 + r] : 0;
    red[threadIdx.x] = s;
    __syncthreads();
    for (int off = 128; off > 0; off >>= 1) {
        if (threadIdx.x < off) red[threadIdx.x] += red[threadIdx.x + off];
        __syncthreads();
    }
    if (threadIdx.x == 0) partial[blockIdx.x] = red[0];
}

__global__ __launch_bounds__(128) void scan_mid(int* __restrict__ partial, int nb,
                                                int* __restrict__ offs, int n) {
    __shared__ int s[128];
    int v = (threadIdx.x < nb) ? partial[threadIdx.x] : 0;
    s[threadIdx.x] = v;
    __syncthreads();
    for (int off = 1; off < 128; off <<= 1) {
        int t = (threadIdx.x >= off) ? s[threadIdx.x - off] : 0;
        __syncthreads();
        s[threadIdx.x] += t;
        __syncthreads();
    }
    if (threadIdx.x < nb) partial[threadIdx.x] = s[threadIdx.x] - v;   // exclusive
    if (threadIdx.x == nb - 1) offs[n] = s[threadIdx.x];               // total
}

__global__ __launch_bounds__(256) void scan_final(const int* __restrict__ deg,
                                                  const int* __restrict__ partial,
                                                  int* __restrict__ offs,
                                                  int* __restrict__ cursor, int n) {
    __shared__ int s[256];
    int i0 = blockIdx.x * 1024 + threadIdx.x * 4;
    int v[4];
    int sum = 0;
#pragma unroll
    for (int r = 0; r < 4; ++r) {
        v[r] = (i0 + r < n) ? deg[i0 + r] : 0;
        sum += v[r];
    }
    s[threadIdx.x] = sum;
    __syncthreads();
    for (int off = 1; off < 256; off <<= 1) {
        int t = (threadIdx.x >= off) ? s[threadIdx.x - off] : 0;
        __syncthreads();
        s[threadIdx.x] += t;
        __syncthreads();
    }
    int excl = s[threadIdx.x] - sum + partial[blockIdx.x];
#pragma unroll
    for (int r = 0; r < 4; ++r) {
        if (i0 + r < n) { offs[i0 + r] = excl; cursor[i0 + r] = excl; }
        excl += v[r];
    }
}

__global__ __launch_bounds__(256) void edge_fill(const int* __restrict__ ei, int E, int n,
                                                 int* __restrict__ cursor,
                                                 int* __restrict__ csr) {
    int e = blockIdx.x * blockDim.x + threadIdx.x;
    int Etot = E + n;
    if (e >= Etot) return;
    int src, dst;
    if (e < E) { src = ei[e]; dst = ei[E + e]; }
    else       { src = e - E; dst = e - E; }
    int pos = atomicAdd(&cursor[dst], 1);
    csr[pos] = src;
}

// -------- Pack W into MFMA-fragment-major hi/lo bf16 ----------------------

__global__ __launch_bounds__(256) void pack_frag(const float* __restrict__ W,
                                                 u16* __restrict__ Bhi,
                                                 u16* __restrict__ Blo, int N) {
    int CT = N / 16;
    int idx = blockIdx.x * blockDim.x + threadIdx.x;
    if (idx >= 8 * CT * 64) return;
    int lane = idx & 63;
    int ctkb = idx >> 6;
    int ct = ctkb % CT;
    int kb = ctkb / CT;
    int col = ct * 16 + (lane & 15);
    int k0 = kb * 32 + (lane >> 4) * 8;
#pragma unroll
    for (int j = 0; j < 8; ++j) {
        float w = W[(size_t)(k0 + j) * N + col];
        u16 hi = f2b(w);
        Bhi[(size_t)idx * 8 + j] = hi;
        Blo[(size_t)idx * 8 + j] = f2b(w - b2f(hi));
    }
}

// ------- Layer-1 linear (K=3) + fused scores; writes bf16 shadow only -----

__global__ __launch_bounds__(256) void linear1(const float* __restrict__ x,
                                               const float* __restrict__ W,
                                               const float* __restrict__ asrc,
                                               const float* __restrict__ adst,
                                               u16* __restrict__ Hb,
                                               float* __restrict__ ssrc,
                                               float* __restrict__ sdst, int n) {
    int node = blockIdx.x;
    if (node >= n) return;
    int c = threadIdx.x;
    int head = c >> 6, lane = c & 63;
    float x0 = x[node * 3 + 0], x1 = x[node * 3 + 1], x2 = x[node * 3 + 2];
    float v = fmaf(x0, W[c], fmaf(x1, W[256 + c], x2 * W[512 + c]));
    Hb[(size_t)node * 256 + c] = f2b(v);
    float va = v * asrc[c];
    float vb = v * adst[c];
#pragma unroll
    for (int o = 32; o > 0; o >>= 1) {
        va += __shfl_xor(va, o);
        vb += __shfl_xor(vb, o);
    }
    if (lane == 0) { ssrc[node * 4 + head] = va; sdst[node * 4 + head] = vb; }
}

// ------- Async 2-phase split-precision MFMA GEMM, BM=128 / 8 waves --------
// out = A[n x 256] * W^T (NCOLS = CT*16). A pre-split hi/lo bf16 (producer-
// written). D = Ahi*Whi + Alo*Whi + Ahi*Wlo (fp32 acc).
// B: double-buffered LDS via global_load_lds (fragment-major linear;
//    64 lanes read consecutive 16B chunks -> conflict-free ds_read_b128).
//    Staged ONCE per 128 rows (2x amortization vs BM=64).
// A: direct global->VGPR bf16x8 loads with 1-deep register prefetch.
// 391 blocks @ 2/CU -> fully co-resident, no dispatch tail.
// Fragments: A[m=lane&15][k=(lane>>4)*8+j]; D reg r -> row (l>>4)*4+r, col l&15.

template <int CT, int HEADS>
__global__ __launch_bounds__(512, 4) void gemm_async(const u16* __restrict__ Ahi,
                                                     const u16* __restrict__ Alo,
                                                     const u16* __restrict__ Bhi,
                                                     const u16* __restrict__ Blo,
                                                     const float* __restrict__ asrc,
                                                     const float* __restrict__ adst,
                                                     u16* __restrict__ Hb,
                                                     float* __restrict__ ssrc,
                                                     float* __restrict__ sdst, int n) {
    constexpr int THREADS = 512;
    constexpr int BFRAG = CT * 64;          // B 16B-chunks per kb per array
    constexpr int BSZ = BFRAG * 8;          // u16 per B array per kb slice
    __shared__ __align__(16) u16 lds[2][2 * BSZ];

    int t = threadIdx.x;
    int w = t >> 6, l = t & 63;
    int m0 = blockIdx.x * 128 + w * 16;     // 8 waves x 16 rows = 128 rows
    int lm = l & 15, q = l >> 4;

    int arow = min(m0 + lm, n - 1);         // clamp OOB rows (stores guarded)
    const u16* aH = Ahi + (size_t)arow * 256 + q * 8;
    const u16* aL = Alo + (size_t)arow * 256 + q * 8;

    floatx4 acc[CT] = {};

    auto stageB = [&](int buf, int kb) {
        u16* L = &lds[buf][0];
        constexpr int BROUNDS = (BFRAG + THREADS - 1) / THREADS;
#pragma unroll
        for (int r = 0; r < BROUNDS; ++r) {
            int u = r * THREADS + t;
            if ((BFRAG % THREADS == 0) || u < BFRAG) {
                size_t off = ((size_t)kb * BFRAG + (size_t)u) * 8;
                u16* Lb = L + (size_t)(r * THREADS + w * 64) * 8;   // wave-uniform
                load16(Bhi + off, Lb);
                load16(Blo + off, Lb + BSZ);
            }
        }
    };

    stageB(0, 0);
    bf16x8 ahi = *(const bf16x8*)aH;        // kb=0 A fragments
    bf16x8 alo = *(const bf16x8*)aL;
    __syncthreads();    // implicit vmcnt(0): buf0 + A loads done

    for (int kb = 0; kb < 8; ++kb) {
        int cur = kb & 1;
        bf16x8 nhi = ahi, nlo = alo;
        if (kb < 7) {
            stageB(cur ^ 1, kb + 1);                      // async B prefetch
            nhi = *(const bf16x8*)(aH + (kb + 1) * 32);   // A reg prefetch
            nlo = *(const bf16x8*)(aL + (kb + 1) * 32);
        }
        const u16* L = &lds[cur][0];
#pragma unroll
        for (int ct = 0; ct < CT; ++ct) {
            bf16x8 bhi = *(const bf16x8*)&L[(ct * 64 + l) * 8];
            bf16x8 blo = *(const bf16x8*)&L[BSZ + (ct * 64 + l) * 8];
            acc[ct] = __builtin_amdgcn_mfma_f32_16x16x32_bf16(ahi, bhi, acc[ct], 0, 0, 0);
            acc[ct] = __builtin_amdgcn_mfma_f32_16x16x32_bf16(alo, bhi, acc[ct], 0, 0, 0);
            acc[ct] = __builtin_amdgcn_mfma_f32_16x16x32_bf16(ahi, blo, acc[ct], 0, 0, 0);
        }
        __syncthreads();   // drains next-tile stage + A prefetch (vmcnt 0)
        ahi = nhi; alo = nlo;
    }

    // ---- bf16 shadow store ----
#pragma unroll
    for (int ct = 0; ct < CT; ++ct) {
#pragma unroll
        for (int r = 0; r < 4; ++r) {
            int row = m0 + q * 4 + r;
            if (row < n)
                Hb[(size_t)row * (CT * 16) + ct * 16 + lm] = f2b(acc[ct][r]);
        }
    }
    // ---- fused scores: per-row, per-head dot with asrc/adst -------------
    constexpr int CPH = CT / HEADS;          // col-tiles per head
    float ps[4][HEADS] = {}, pd[4][HEADS] = {};
#pragma unroll
    for (int h = 0; h < HEADS; ++h) {
#pragma unroll
        for (int j = 0; j < CPH; ++j) {
            int ct = h * CPH + j;
            float a_s = asrc[ct * 16 + lm];
            float a_d = adst[ct * 16 + lm];
#pragma unroll
            for (int r = 0; r < 4; ++r) {
                ps[r][h] = fmaf(acc[ct][r], a_s, ps[r][h]);
                pd[r][h] = fmaf(acc[ct][r], a_d, pd[r][h]);
            }
        }
    }
#pragma unroll
    for (int r = 0; r < 4; ++r)
#pragma unroll
        for (int h = 0; h < HEADS; ++h)
#pragma unroll
            for (int o = 1; o < 16; o <<= 1) {
                ps[r][h] += __shfl_xor(ps[r][h], o);
                pd[r][h] += __shfl_xor(pd[r][h], o);
            }
#pragma unroll
    for (int h = 0; h < HEADS; ++h) {
        if (lm == h) {
#pragma unroll
            for (int r = 0; r < 4; ++r) {
                int row = m0 + q * 4 + r;
                if (row < n) {
                    ssrc[row * HEADS + h] = ps[r][h];
                    sdst[row * HEADS + h] = pd[r][h];
                }
            }
        }
    }
}

// ---------------- Merged 4-head aggregation (layers 1 & 2) ----------------
// One wave per dst node (R10 structure). Lane l: fp32 float4 acc (channels
// l*4..+3, head hA=l>>4); softmax state head hB=l&3, edge slot eL=l>>2.
// Values gathered bf16 (ushort4), logits fp32-exact from ssrc/sdst tables.
// Epilogue writes the hi/lo bf16 decomposition of relu(acc/l + bias).

__global__ __launch_bounds__(256) void gat_aggregate_m4(const u16* __restrict__ Hb,
                                                        const float* __restrict__ ssrc,
                                                        const float* __restrict__ sdst,
                                                        const int* __restrict__ offs,
                                                        const int* __restrict__ csr,
                                                        const float* __restrict__ bias,
                                                        u16* __restrict__ outHi,
                                                        u16* __restrict__ outLo, int n) {
    int node = blockIdx.x * 4 + (threadIdx.x >> 6);
    int lane = threadIdx.x & 63;
    if (node >= n) return;
    const int hB = lane & 3;
    const int eL = lane >> 2;
    const int hA = lane >> 4;
    int beg = offs[node], end = offs[node + 1];
    float sd = sdst[node * 4 + hB];
    float m = -INFINITY, l = 0.f;
    float4 acc = make_float4(0.f, 0.f, 0.f, 0.f);

    for (int base = beg; base < end; base += 16) {
        int j = base + eL;
        bool valid = (j < end);
        int sj = valid ? csr[j] : 0;
        float logit = -INFINITY;
        if (valid) {
            float xv = ssrc[sj * 4 + hB] + sd;
            logit = (xv > 0.f) ? xv : NEG_SLOPE * xv;
        }
        float cm = logit;
        cm = fmaxf(cm, __shfl_xor(cm, 4));
        cm = fmaxf(cm, __shfl_xor(cm, 8));
        cm = fmaxf(cm, __shfl_xor(cm, 16));
        cm = fmaxf(cm, __shfl_xor(cm, 32));
        float nm = fmaxf(m, cm);
        float scale = __expf(m - nm);       // m=-inf -> 0
        float ex = valid ? __expf(logit - nm) : 0.f;
        float es = ex;
        es += __shfl_xor(es, 4);
        es += __shfl_xor(es, 8);
        es += __shfl_xor(es, 16);
        es += __shfl_xor(es, 32);
        l = l * scale + es;
        m = nm;
        float sA = __shfl(scale, hA);
        acc.x *= sA; acc.y *= sA; acc.z *= sA; acc.w *= sA;

        int cnt = min(16, end - base);
        for (int t = 0; t < cnt; t += 4) {
#pragma unroll
            for (int u = 0; u < 4; ++u) {
                int tt = t + u;
                float a = __shfl(ex, tt * 4 + hA);   // 0 for invalid edges
                int s = __shfl(sj, tt * 4);          // 0 for invalid (safe addr)
                ushort4 hv = *(const ushort4*)&Hb[(size_t)s * 256 + lane * 4];
                acc.x = fmaf(a, b2f(hv.x), acc.x);
                acc.y = fmaf(a, b2f(hv.y), acc.y);
                acc.z = fmaf(a, b2f(hv.z), acc.z);
                acc.w = fmaf(a, b2f(hv.w), acc.w);
            }
        }
    }
    float lf = __shfl(l, hA);
    float inv = 1.f / lf;
    const float4 bv = *(const float4*)&bias[lane * 4];
    float4 o;
    o.x = fmaxf(fmaf(acc.x, inv, bv.x), 0.f);   // relu (layers 1 & 2)
    o.y = fmaxf(fmaf(acc.y, inv, bv.y), 0.f);
    o.z = fmaxf(fmaf(acc.z, inv, bv.z), 0.f);
    o.w = fmaxf(fmaf(acc.w, inv, bv.w), 0.f);
    ushort4 h4, l4;
    h4.x = f2b(o.x); l4.x = f2b(o.x - b2f(h4.x));
    h4.y = f2b(o.y); l4.y = f2b(o.y - b2f(h4.y));
    h4.z = f2b(o.z); l4.z = f2b(o.z - b2f(h4.z));
    h4.w = f2b(o.w); l4.w = f2b(o.w - b2f(h4.w));
    *(ushort4*)&outHi[(size_t)node * 256 + lane * 4] = h4;
    *(ushort4*)&outLo[(size_t)node * 256 + lane * 4] = l4;
}

// ---------------- Single-head aggregation (layer 3, C=32, no relu) --------

__global__ __launch_bounds__(256) void gat_aggregate_h1(const u16* __restrict__ Hb,
                                                        const float* __restrict__ ssrc,
                                                        const float* __restrict__ sdst,
                                                        const int* __restrict__ offs,
                                                        const int* __restrict__ csr,
                                                        const float* __restrict__ bias,
                                                        float* __restrict__ out, int n) {
    int node = blockIdx.x * 4 + (threadIdx.x >> 6);
    int lane = threadIdx.x & 63;
    if (node >= n) return;
    int beg = offs[node], end = offs[node + 1];
    float sd = sdst[node];
    float m = -INFINITY, l = 0.f, acc = 0.f;

    for (int base = beg; base < end; base += 64) {
        int j = base + lane;
        bool valid = (j < end);
        int sj = valid ? csr[j] : 0;
        float logit = -INFINITY;
        if (valid) {
            float xv = ssrc[sj] + sd;
            logit = (xv > 0.f) ? xv : NEG_SLOPE * xv;
        }
        float cm = logit;
#pragma unroll
        for (int o = 32; o > 0; o >>= 1) cm = fmaxf(cm, __shfl_xor(cm, o));
        float nm = fmaxf(m, cm);
        float scale = __expf(m - nm);
        float ex = valid ? __expf(logit - nm) : 0.f;
        float es = ex;
#pragma unroll
        for (int o = 32; o > 0; o >>= 1) es += __shfl_xor(es, o);
        l = l * scale + es;
        m = nm;
        acc *= scale;
        int cnt = min(64, end - base);
        for (int t = 0; t < cnt; t += 4) {
#pragma unroll
            for (int u = 0; u < 4; ++u) {
                float a = __shfl(ex, t + u);
                int s = __shfl(sj, t + u);
                if (lane < 32) acc = fmaf(a, b2f(Hb[(size_t)s * 32 + lane]), acc);
            }
        }
    }
    if (lane < 32) out[(size_t)node * 32 + lane] = acc / l + bias[lane];
}

// ---------------- Launch ----------------

extern "C" void kernel_launch(void* const* d_in, const int* in_sizes, int n_in,
                              void* d_out, int out_size, void* d_ws, size_t ws_size,
                              hipStream_t stream) {
    const float* x   = (const float*)d_in[0];
    const int*   ei  = (const int*)d_in[1];
    const float* W1  = (const float*)d_in[2];
    const float* as1 = (const float*)d_in[3];
    const float* ad1 = (const float*)d_in[4];
    const float* b1  = (const float*)d_in[5];
    const float* W2  = (const float*)d_in[6];
    const float* as2 = (const float*)d_in[7];
    const float* ad2 = (const float*)d_in[8];
    const float* b2  = (const float*)d_in[9];
    const float* W3  = (const float*)d_in[10];
    const float* as3 = (const float*)d_in[11];
    const float* ad3 = (const float*)d_in[12];
    const float* b3  = (const float*)d_in[13];
    float* out = (float*)d_out;

    const int n = in_sizes[0] / 3;     // 50000
    const int E = in_sizes[1] / 2;     // 400000
    const int Etot = E + n;            // with self-loops

    // workspace layout (~84 MB)
    char* ws = (char*)d_ws;
    u16* Fhi  = (u16*)ws;    ws += (size_t)n * 256 * sizeof(u16);     // 25.6 MB split hi
    u16* Flo  = (u16*)ws;    ws += (size_t)n * 256 * sizeof(u16);     // 25.6 MB split lo
    u16* Hb   = (u16*)ws;    ws += (size_t)n * 256 * sizeof(u16);     // 25.6 MB bf16 shadow
    u16* Hb3  = (u16*)ws;    ws += (size_t)n * 32 * sizeof(u16);      // 3.2 MB
    u16* B2h  = (u16*)ws;    ws += (size_t)8 * 16 * 64 * 8 * sizeof(u16);
    u16* B2l  = (u16*)ws;    ws += (size_t)8 * 16 * 64 * 8 * sizeof(u16);
    u16* B3h  = (u16*)ws;    ws += (size_t)8 * 2 * 64 * 8 * sizeof(u16);
    u16* B3l  = (u16*)ws;    ws += (size_t)8 * 2 * 64 * 8 * sizeof(u16);
    float* ssrc = (float*)ws;  ws += (size_t)n * 4 * sizeof(float);
    float* sdst = (float*)ws;  ws += (size_t)n * 4 * sizeof(float);
    int* deg    = (int*)ws;    ws += (size_t)n * sizeof(int);
    int* offs   = (int*)ws;    ws += (size_t)(n + 1) * sizeof(int) + 12;
    int* cursor = (int*)ws;    ws += (size_t)n * sizeof(int);
    int* partial = (int*)ws;   ws += (size_t)128 * sizeof(int);
    int* csr    = (int*)ws;    ws += (size_t)Etot * sizeof(int);   // keep csr LAST

    // ---- CSR build (by dst) ----
    hipMemsetAsync(deg, 0, (size_t)n * sizeof(int), stream);
    int eblocks = (Etot + 255) / 256;
    edge_count<<<eblocks, 256, 0, stream>>>(ei, E, n, deg);
    int sb = (n + 1023) / 1024;
    scan_partials<<<sb, 256, 0, stream>>>(deg, partial, n);
    scan_mid<<<1, 128, 0, stream>>>(partial, sb, offs, n);
    scan_final<<<sb, 256, 0, stream>>>(deg, partial, offs, cursor, n);
    edge_fill<<<eblocks, 256, 0, stream>>>(ei, E, n, cursor, csr);

    // ---- Weight prep (fragment-major hi/lo pack) ----
    pack_frag<<<(8 * 16 * 64 + 255) / 256, 256, 0, stream>>>(W2, B2h, B2l, 256);
    pack_frag<<<(8 * 2 * 64 + 255) / 256, 256, 0, stream>>>(W3, B3h, B3l, 32);

    int nb4 = (n + 3) / 4;
    int nb128 = (n + 127) / 128;       // 391 blocks, 2/CU -> no tail

    // ---- Layer 1: 3 -> (4 x 64), concat, relu ----
    linear1<<<n, 256, 0, stream>>>(x, W1, as1, ad1, Hb, ssrc, sdst, n);
    gat_aggregate_m4<<<nb4, 256, 0, stream>>>(Hb, ssrc, sdst, offs, csr, b1, Fhi, Flo, n);

    // ---- Layer 2: 256 -> (4 x 64), concat, relu ----
    gemm_async<16, 4><<<nb128, 512, 0, stream>>>(Fhi, Flo, B2h, B2l, as2, ad2, Hb, ssrc, sdst, n);
    gat_aggregate_m4<<<nb4, 256, 0, stream>>>(Hb, ssrc, sdst, offs, csr, b2, Fhi, Flo, n);

    // ---- Layer 3: 256 -> (1 x 32), mean(=identity), no relu ----
    gemm_async<2, 1><<<nb128, 512, 0, stream>>>(Fhi, Flo, B3h, B3l, as3, ad3, Hb3, ssrc, sdst, n);
    gat_aggregate_h1<<<nb4, 256, 0, stream>>>(Hb3, ssrc, sdst, offs, csr, b3, out, n);
}

// Round 6
// 291.799 us; speedup vs baseline: 1.2380x; 1.1336x over previous
//
#include <hip/hip_runtime.h>
#include <math.h>

// =====================================================================
// 3-layer GAT (PyG GATConv) on MI355X.
// R14: layer-1 aggregation in x-space.
//  - Sum-then-project: sum_e alpha*(x W1) = (sum_e alpha*x) W1, and
//    s_src = x*(W1 a_src) (3-dot). l1_prep computes v_s/v_d (4x3) once;
//    gat_aggregate_l1 gathers 12 B x-rows (L2-resident), does softmax +
//    shuffle-only consume, applies W1 in the epilogue. linear1 deleted.
//  - Layers 2/3 unchanged: BM=128 8-wave async split-precision GEMMs,
//    R10-form aggregations (bf16 value gather, fp32 softmax/accum).
// =====================================================================

#define NEG_SLOPE 0.2f

typedef unsigned short u16;
typedef short bf16x8 __attribute__((ext_vector_type(8)));
typedef float floatx4 __attribute__((ext_vector_type(4)));

__device__ __forceinline__ float b2f(u16 u) {
    return __uint_as_float(((unsigned int)u) << 16);
}
__device__ __forceinline__ u16 f2b(float f) {
    unsigned int u = __float_as_uint(f);
    unsigned int r = (u + 0x7fffu + ((u >> 16) & 1u)) >> 16;   // RNE
    return (u16)r;
}

// async 16B global -> LDS (DMA, no VGPR round-trip). LDS dest must be
// wave-uniform base; HW adds lane*16. Global source is per-lane.
__device__ __forceinline__ void load16(const u16* g, u16* l) {
    __builtin_amdgcn_global_load_lds(
        (const __attribute__((address_space(1))) void*)g,
        (__attribute__((address_space(3))) void*)l, 16, 0, 0);
}

// ---------------- CSR build ----------------

__global__ __launch_bounds__(256) void edge_count(const int* __restrict__ ei, int E, int n,
                                                  int* __restrict__ deg) {
    int e = blockIdx.x * blockDim.x + threadIdx.x;
    int Etot = E + n;
    if (e >= Etot) return;
    int dst = (e < E) ? ei[E + e] : (e - E);   // self-loop for e >= E
    atomicAdd(&deg[dst], 1);
}

__global__ __launch_bounds__(256) void scan_partials(const int* __restrict__ deg,
                                                     int* __restrict__ partial, int n) {
    __shared__ int red[256];
    int i0 = blockIdx.x * 1024 + threadIdx.x * 4;
    int s = 0;
#pragma unroll
    for (int r = 0; r < 4; ++r) s += (i0 + r < n) ? deg[i0 + r] : 0;
    red[threadIdx.x] = s;
    __syncthreads();
    for (int off = 128; off > 0; off >>= 1) {
        if (threadIdx.x < off) red[threadIdx.x] += red[threadIdx.x + off];
        __syncthreads();
    }
    if (threadIdx.x == 0) partial[blockIdx.x] = red[0];
}

__global__ __launch_bounds__(128) void scan_mid(int* __restrict__ partial, int nb,
                                                int* __restrict__ offs, int n) {
    __shared__ int s[128];
    int v = (threadIdx.x < nb) ? partial[threadIdx.x] : 0;
    s[threadIdx.x] = v;
    __syncthreads();
    for (int off = 1; off < 128; off <<= 1) {
        int t = (threadIdx.x >= off) ? s[threadIdx.x - off] : 0;
        __syncthreads();
        s[threadIdx.x] += t;
        __syncthreads();
    }
    if (threadIdx.x < nb) partial[threadIdx.x] = s[threadIdx.x] - v;   // exclusive
    if (threadIdx.x == nb - 1) offs[n] = s[threadIdx.x];               // total
}

__global__ __launch_bounds__(256) void scan_final(const int* __restrict__ deg,
                                                  const int* __restrict__ partial,
                                                  int* __restrict__ offs,
                                                  int* __restrict__ cursor, int n) {
    __shared__ int s[256];
    int i0 = blockIdx.x * 1024 + threadIdx.x * 4;
    int v[4];
    int sum = 0;
#pragma unroll
    for (int r = 0; r < 4; ++r) {
        v[r] = (i0 + r < n) ? deg[i0 + r] : 0;
        sum += v[r];
    }
    s[threadIdx.x] = sum;
    __syncthreads();
    for (int off = 1; off < 256; off <<= 1) {
        int t = (threadIdx.x >= off) ? s[threadIdx.x - off] : 0;
        __syncthreads();
        s[threadIdx.x] += t;
        __syncthreads();
    }
    int excl = s[threadIdx.x] - sum + partial[blockIdx.x];
#pragma unroll
    for (int r = 0; r < 4; ++r) {
        if (i0 + r < n) { offs[i0 + r] = excl; cursor[i0 + r] = excl; }
        excl += v[r];
    }
}

__global__ __launch_bounds__(256) void edge_fill(const int* __restrict__ ei, int E, int n,
                                                 int* __restrict__ cursor,
                                                 int* __restrict__ csr) {
    int e = blockIdx.x * blockDim.x + threadIdx.x;
    int Etot = E + n;
    if (e >= Etot) return;
    int src, dst;
    if (e < E) { src = ei[e]; dst = ei[E + e]; }
    else       { src = e - E; dst = e - E; }
    int pos = atomicAdd(&cursor[dst], 1);
    csr[pos] = src;
}

// -------- Pack W into MFMA-fragment-major hi/lo bf16 ----------------------

__global__ __launch_bounds__(256) void pack_frag(const float* __restrict__ W,
                                                 u16* __restrict__ Bhi,
                                                 u16* __restrict__ Blo, int N) {
    int CT = N / 16;
    int idx = blockIdx.x * blockDim.x + threadIdx.x;
    if (idx >= 8 * CT * 64) return;
    int lane = idx & 63;
    int ctkb = idx >> 6;
    int ct = ctkb % CT;
    int kb = ctkb / CT;
    int col = ct * 16 + (lane & 15);
    int k0 = kb * 32 + (lane >> 4) * 8;
#pragma unroll
    for (int j = 0; j < 8; ++j) {
        float w = W[(size_t)(k0 + j) * N + col];
        u16 hi = f2b(w);
        Bhi[(size_t)idx * 8 + j] = hi;
        Blo[(size_t)idx * 8 + j] = f2b(w - b2f(hi));
    }
}

// -------- Layer-1 prep: v_s[h][k] = sum_c W1[k, h*64+c]*a_src1[h,c] -------
// vsd layout: [0..11] = vs[h*3+k], [12..23] = vd[h*3+k].

__global__ __launch_bounds__(256) void l1_prep(const float* __restrict__ W1,
                                               const float* __restrict__ as1,
                                               const float* __restrict__ ad1,
                                               float* __restrict__ vsd) {
    int j = threadIdx.x;          // 0..255; head = j>>6 (one wave per head)
    int lane = j & 63;
    float a_s = as1[j], a_d = ad1[j];
#pragma unroll
    for (int k = 0; k < 3; ++k) {
        float w = W1[k * 256 + j];
        float ps = w * a_s, pd = w * a_d;
#pragma unroll
        for (int o = 32; o > 0; o >>= 1) {
            ps += __shfl_xor(ps, o);
            pd += __shfl_xor(pd, o);
        }
        if (lane == 0) {
            vsd[(j >> 6) * 3 + k] = ps;
            vsd[12 + (j >> 6) * 3 + k] = pd;
        }
    }
}

// ---------------- Layer-1 aggregation in x-space --------------------------
// One wave per dst node. Softmax lanes: head hB=lane&3, edge slot eL=lane>>2
// (s_src computed on the fly: 3-dot of gathered x row with v_s[hB]).
// Aggregate state: ax,ay,az = sum_e alpha_{e,hA} * x[src_e] (head hA=lane>>4)
// -- consume is shuffle-only (x rows already in softmax lanes' registers).
// Epilogue: out[c=lane*4+j] = relu((aggx/l) . W1[:,c] + b1[c]), hi/lo bf16.

__global__ __launch_bounds__(256) void gat_aggregate_l1(const float* __restrict__ x,
                                                        const float* __restrict__ vsd,
                                                        const int* __restrict__ offs,
                                                        const int* __restrict__ csr,
                                                        const float* __restrict__ W1,
                                                        const float* __restrict__ bias,
                                                        u16* __restrict__ outHi,
                                                        u16* __restrict__ outLo, int n) {
    int node = blockIdx.x * 4 + (threadIdx.x >> 6);
    int lane = threadIdx.x & 63;
    if (node >= n) return;
    const int hB = lane & 3;
    const int eL = lane >> 2;
    const int hA = lane >> 4;
    int beg = offs[node], end = offs[node + 1];

    float vs0 = vsd[hB * 3 + 0], vs1 = vsd[hB * 3 + 1], vs2 = vsd[hB * 3 + 2];
    float vd0 = vsd[12 + hB * 3 + 0], vd1 = vsd[12 + hB * 3 + 1], vd2 = vsd[12 + hB * 3 + 2];
    float xd0 = x[node * 3 + 0], xd1 = x[node * 3 + 1], xd2 = x[node * 3 + 2];
    float sd = fmaf(xd0, vd0, fmaf(xd1, vd1, xd2 * vd2));

    float m = -INFINITY, l = 0.f;
    float ax = 0.f, ay = 0.f, az = 0.f;

    for (int base = beg; base < end; base += 16) {
        int j = base + eL;
        bool valid = (j < end);
        int sj = valid ? csr[j] : 0;
        float x0 = x[sj * 3 + 0];          // 12B gather, L2-resident table
        float x1 = x[sj * 3 + 1];
        float x2 = x[sj * 3 + 2];
        float logit = -INFINITY;
        if (valid) {
            float xv = fmaf(x0, vs0, fmaf(x1, vs1, x2 * vs2)) + sd;
            logit = (xv > 0.f) ? xv : NEG_SLOPE * xv;
        }
        float cm = logit;
        cm = fmaxf(cm, __shfl_xor(cm, 4));
        cm = fmaxf(cm, __shfl_xor(cm, 8));
        cm = fmaxf(cm, __shfl_xor(cm, 16));
        cm = fmaxf(cm, __shfl_xor(cm, 32));
        float nm = fmaxf(m, cm);
        float scale = __expf(m - nm);       // m=-inf -> 0
        float ex = valid ? __expf(logit - nm) : 0.f;
        float es = ex;
        es += __shfl_xor(es, 4);
        es += __shfl_xor(es, 8);
        es += __shfl_xor(es, 16);
        es += __shfl_xor(es, 32);
        l = l * scale + es;
        m = nm;
        float sA = __shfl(scale, hA);
        ax *= sA; ay *= sA; az *= sA;

        int cnt = min(16, end - base);
        for (int t = 0; t < cnt; ++t) {
            float a  = __shfl(ex, t * 4 + hA);   // alpha (unnorm) for head hA
            float bx = __shfl(x0, t * 4);
            float by = __shfl(x1, t * 4);
            float bz = __shfl(x2, t * 4);
            ax = fmaf(a, bx, ax);
            ay = fmaf(a, by, ay);
            az = fmaf(a, bz, az);
        }
    }

    float lf = __shfl(l, hA);
    float inv = 1.f / lf;
    ax *= inv; ay *= inv; az *= inv;

    int c = lane * 4;
    const float4 w0 = *(const float4*)&W1[0 * 256 + c];
    const float4 w1 = *(const float4*)&W1[1 * 256 + c];
    const float4 w2 = *(const float4*)&W1[2 * 256 + c];
    const float4 bv = *(const float4*)&bias[c];
    float4 o;
    o.x = fmaxf(fmaf(ax, w0.x, fmaf(ay, w1.x, fmaf(az, w2.x, bv.x))), 0.f);
    o.y = fmaxf(fmaf(ax, w0.y, fmaf(ay, w1.y, fmaf(az, w2.y, bv.y))), 0.f);
    o.z = fmaxf(fmaf(ax, w0.z, fmaf(ay, w1.z, fmaf(az, w2.z, bv.z))), 0.f);
    o.w = fmaxf(fmaf(ax, w0.w, fmaf(ay, w1.w, fmaf(az, w2.w, bv.w))), 0.f);
    ushort4 h4, l4;
    h4.x = f2b(o.x); l4.x = f2b(o.x - b2f(h4.x));
    h4.y = f2b(o.y); l4.y = f2b(o.y - b2f(h4.y));
    h4.z = f2b(o.z); l4.z = f2b(o.z - b2f(h4.z));
    h4.w = f2b(o.w); l4.w = f2b(o.w - b2f(h4.w));
    *(ushort4*)&outHi[(size_t)node * 256 + c] = h4;
    *(ushort4*)&outLo[(size_t)node * 256 + c] = l4;
}

// ------- Async 2-phase split-precision MFMA GEMM, BM=128 / 8 waves --------
// out = A[n x 256] * W^T (NCOLS = CT*16). A pre-split hi/lo bf16 (producer-
// written). D = Ahi*Whi + Alo*Whi + Ahi*Wlo (fp32 acc).
// B: double-buffered LDS via global_load_lds (fragment-major linear;
//    64 lanes read consecutive 16B chunks -> conflict-free ds_read_b128).
//    Staged ONCE per 128 rows. A: direct global->VGPR, 1-deep prefetch.
// 391 blocks @ 2/CU -> fully co-resident, no dispatch tail.
// Fragments: A[m=lane&15][k=(lane>>4)*8+j]; D reg r -> row (l>>4)*4+r, col l&15.

template <int CT, int HEADS>
__global__ __launch_bounds__(512, 4) void gemm_async(const u16* __restrict__ Ahi,
                                                     const u16* __restrict__ Alo,
                                                     const u16* __restrict__ Bhi,
                                                     const u16* __restrict__ Blo,
                                                     const float* __restrict__ asrc,
                                                     const float* __restrict__ adst,
                                                     u16* __restrict__ Hb,
                                                     float* __restrict__ ssrc,
                                                     float* __restrict__ sdst, int n) {
    constexpr int THREADS = 512;
    constexpr int BFRAG = CT * 64;          // B 16B-chunks per kb per array
    constexpr int BSZ = BFRAG * 8;          // u16 per B array per kb slice
    __shared__ __align__(16) u16 lds[2][2 * BSZ];

    int t = threadIdx.x;
    int w = t >> 6, l = t & 63;
    int m0 = blockIdx.x * 128 + w * 16;     // 8 waves x 16 rows = 128 rows
    int lm = l & 15, q = l >> 4;

    int arow = min(m0 + lm, n - 1);         // clamp OOB rows (stores guarded)
    const u16* aH = Ahi + (size_t)arow * 256 + q * 8;
    const u16* aL = Alo + (size_t)arow * 256 + q * 8;

    floatx4 acc[CT] = {};

    auto stageB = [&](int buf, int kb) {
        u16* L = &lds[buf][0];
        constexpr int BROUNDS = (BFRAG + THREADS - 1) / THREADS;
#pragma unroll
        for (int r = 0; r < BROUNDS; ++r) {
            int u = r * THREADS + t;
            if ((BFRAG % THREADS == 0) || u < BFRAG) {
                size_t off = ((size_t)kb * BFRAG + (size_t)u) * 8;
                u16* Lb = L + (size_t)(r * THREADS + w * 64) * 8;   // wave-uniform
                load16(Bhi + off, Lb);
                load16(Blo + off, Lb + BSZ);
            }
        }
    };

    stageB(0, 0);
    bf16x8 ahi = *(const bf16x8*)aH;        // kb=0 A fragments
    bf16x8 alo = *(const bf16x8*)aL;
    __syncthreads();    // implicit vmcnt(0): buf0 + A loads done

    for (int kb = 0; kb < 8; ++kb) {
        int cur = kb & 1;
        bf16x8 nhi = ahi, nlo = alo;
        if (kb < 7) {
            stageB(cur ^ 1, kb + 1);                      // async B prefetch
            nhi = *(const bf16x8*)(aH + (kb + 1) * 32);   // A reg prefetch
            nlo = *(const bf16x8*)(aL + (kb + 1) * 32);
        }
        const u16* L = &lds[cur][0];
#pragma unroll
        for (int ct = 0; ct < CT; ++ct) {
            bf16x8 bhi = *(const bf16x8*)&L[(ct * 64 + l) * 8];
            bf16x8 blo = *(const bf16x8*)&L[BSZ + (ct * 64 + l) * 8];
            acc[ct] = __builtin_amdgcn_mfma_f32_16x16x32_bf16(ahi, bhi, acc[ct], 0, 0, 0);
            acc[ct] = __builtin_amdgcn_mfma_f32_16x16x32_bf16(alo, bhi, acc[ct], 0, 0, 0);
            acc[ct] = __builtin_amdgcn_mfma_f32_16x16x32_bf16(ahi, blo, acc[ct], 0, 0, 0);
        }
        __syncthreads();   // drains next-tile stage + A prefetch (vmcnt 0)
        ahi = nhi; alo = nlo;
    }

    // ---- bf16 shadow store ----
#pragma unroll
    for (int ct = 0; ct < CT; ++ct) {
#pragma unroll
        for (int r = 0; r < 4; ++r) {
            int row = m0 + q * 4 + r;
            if (row < n)
                Hb[(size_t)row * (CT * 16) + ct * 16 + lm] = f2b(acc[ct][r]);
        }
    }
    // ---- fused scores: per-row, per-head dot with asrc/adst -------------
    constexpr int CPH = CT / HEADS;          // col-tiles per head
    float ps[4][HEADS] = {}, pd[4][HEADS] = {};
#pragma unroll
    for (int h = 0; h < HEADS; ++h) {
#pragma unroll
        for (int j = 0; j < CPH; ++j) {
            int ct = h * CPH + j;
            float a_s = asrc[ct * 16 + lm];
            float a_d = adst[ct * 16 + lm];
#pragma unroll
            for (int r = 0; r < 4; ++r) {
                ps[r][h] = fmaf(acc[ct][r], a_s, ps[r][h]);
                pd[r][h] = fmaf(acc[ct][r], a_d, pd[r][h]);
            }
        }
    }
#pragma unroll
    for (int r = 0; r < 4; ++r)
#pragma unroll
        for (int h = 0; h < HEADS; ++h)
#pragma unroll
            for (int o = 1; o < 16; o <<= 1) {
                ps[r][h] += __shfl_xor(ps[r][h], o);
                pd[r][h] += __shfl_xor(pd[r][h], o);
            }
#pragma unroll
    for (int h = 0; h < HEADS; ++h) {
        if (lm == h) {
#pragma unroll
            for (int r = 0; r < 4; ++r) {
                int row = m0 + q * 4 + r;
                if (row < n) {
                    ssrc[row * HEADS + h] = ps[r][h];
                    sdst[row * HEADS + h] = pd[r][h];
                }
            }
        }
    }
}

// ---------------- Merged 4-head aggregation (layer 2) ---------------------
// One wave per dst node (R10 structure). Lane l: fp32 float4 acc (channels
// l*4..+3, head hA=l>>4); softmax state head hB=l&3, edge slot eL=l>>2.
// Values gathered bf16 (ushort4), logits fp32-exact from ssrc/sdst tables.
// Epilogue writes the hi/lo bf16 decomposition of relu(acc/l + bias).

__global__ __launch_bounds__(256) void gat_aggregate_m4(const u16* __restrict__ Hb,
                                                        const float* __restrict__ ssrc,
                                                        const float* __restrict__ sdst,
                                                        const int* __restrict__ offs,
                                                        const int* __restrict__ csr,
                                                        const float* __restrict__ bias,
                                                        u16* __restrict__ outHi,
                                                        u16* __restrict__ outLo, int n) {
    int node = blockIdx.x * 4 + (threadIdx.x >> 6);
    int lane = threadIdx.x & 63;
    if (node >= n) return;
    const int hB = lane & 3;
    const int eL = lane >> 2;
    const int hA = lane >> 4;
    int beg = offs[node], end = offs[node + 1];
    float sd = sdst[node * 4 + hB];
    float m = -INFINITY, l = 0.f;
    float4 acc = make_float4(0.f, 0.f, 0.f, 0.f);

    for (int base = beg; base < end; base += 16) {
        int j = base + eL;
        bool valid = (j < end);
        int sj = valid ? csr[j] : 0;
        float logit = -INFINITY;
        if (valid) {
            float xv = ssrc[sj * 4 + hB] + sd;
            logit = (xv > 0.f) ? xv : NEG_SLOPE * xv;
        }
        float cm = logit;
        cm = fmaxf(cm, __shfl_xor(cm, 4));
        cm = fmaxf(cm, __shfl_xor(cm, 8));
        cm = fmaxf(cm, __shfl_xor(cm, 16));
        cm = fmaxf(cm, __shfl_xor(cm, 32));
        float nm = fmaxf(m, cm);
        float scale = __expf(m - nm);       // m=-inf -> 0
        float ex = valid ? __expf(logit - nm) : 0.f;
        float es = ex;
        es += __shfl_xor(es, 4);
        es += __shfl_xor(es, 8);
        es += __shfl_xor(es, 16);
        es += __shfl_xor(es, 32);
        l = l * scale + es;
        m = nm;
        float sA = __shfl(scale, hA);
        acc.x *= sA; acc.y *= sA; acc.z *= sA; acc.w *= sA;

        int cnt = min(16, end - base);
        for (int t = 0; t < cnt; t += 4) {
#pragma unroll
            for (int u = 0; u < 4; ++u) {
                int tt = t + u;
                float a = __shfl(ex, tt * 4 + hA);   // 0 for invalid edges
                int s = __shfl(sj, tt * 4);          // 0 for invalid (safe addr)
                ushort4 hv = *(const ushort4*)&Hb[(size_t)s * 256 + lane * 4];
                acc.x = fmaf(a, b2f(hv.x), acc.x);
                acc.y = fmaf(a, b2f(hv.y), acc.y);
                acc.z = fmaf(a, b2f(hv.z), acc.z);
                acc.w = fmaf(a, b2f(hv.w), acc.w);
            }
        }
    }
    float lf = __shfl(l, hA);
    float inv = 1.f / lf;
    const float4 bv = *(const float4*)&bias[lane * 4];
    float4 o;
    o.x = fmaxf(fmaf(acc.x, inv, bv.x), 0.f);   // relu (layers 1 & 2)
    o.y = fmaxf(fmaf(acc.y, inv, bv.y), 0.f);
    o.z = fmaxf(fmaf(acc.z, inv, bv.z), 0.f);
    o.w = fmaxf(fmaf(acc.w, inv, bv.w), 0.f);
    ushort4 h4, l4;
    h4.x = f2b(o.x); l4.x = f2b(o.x - b2f(h4.x));
    h4.y = f2b(o.y); l4.y = f2b(o.y - b2f(h4.y));
    h4.z = f2b(o.z); l4.z = f2b(o.z - b2f(h4.z));
    h4.w = f2b(o.w); l4.w = f2b(o.w - b2f(h4.w));
    *(ushort4*)&outHi[(size_t)node * 256 + lane * 4] = h4;
    *(ushort4*)&outLo[(size_t)node * 256 + lane * 4] = l4;
}

// ---------------- Single-head aggregation (layer 3, C=32, no relu) --------

__global__ __launch_bounds__(256) void gat_aggregate_h1(const u16* __restrict__ Hb,
                                                        const float* __restrict__ ssrc,
                                                        const float* __restrict__ sdst,
                                                        const int* __restrict__ offs,
                                                        const int* __restrict__ csr,
                                                        const float* __restrict__ bias,
                                                        float* __restrict__ out, int n) {
    int node = blockIdx.x * 4 + (threadIdx.x >> 6);
    int lane = threadIdx.x & 63;
    if (node >= n) return;
    int beg = offs[node], end = offs[node + 1];
    float sd = sdst[node];
    float m = -INFINITY, l = 0.f, acc = 0.f;

    for (int base = beg; base < end; base += 64) {
        int j = base + lane;
        bool valid = (j < end);
        int sj = valid ? csr[j] : 0;
        float logit = -INFINITY;
        if (valid) {
            float xv = ssrc[sj] + sd;
            logit = (xv > 0.f) ? xv : NEG_SLOPE * xv;
        }
        float cm = logit;
#pragma unroll
        for (int o = 32; o > 0; o >>= 1) cm = fmaxf(cm, __shfl_xor(cm, o));
        float nm = fmaxf(m, cm);
        float scale = __expf(m - nm);
        float ex = valid ? __expf(logit - nm) : 0.f;
        float es = ex;
#pragma unroll
        for (int o = 32; o > 0; o >>= 1) es += __shfl_xor(es, o);
        l = l * scale + es;
        m = nm;
        acc *= scale;
        int cnt = min(64, end - base);
        for (int t = 0; t < cnt; t += 4) {
#pragma unroll
            for (int u = 0; u < 4; ++u) {
                float a = __shfl(ex, t + u);
                int s = __shfl(sj, t + u);
                if (lane < 32) acc = fmaf(a, b2f(Hb[(size_t)s * 32 + lane]), acc);
            }
        }
    }
    if (lane < 32) out[(size_t)node * 32 + lane] = acc / l + bias[lane];
}

// ---------------- Launch ----------------

extern "C" void kernel_launch(void* const* d_in, const int* in_sizes, int n_in,
                              void* d_out, int out_size, void* d_ws, size_t ws_size,
                              hipStream_t stream) {
    const float* x   = (const float*)d_in[0];
    const int*   ei  = (const int*)d_in[1];
    const float* W1  = (const float*)d_in[2];
    const float* as1 = (const float*)d_in[3];
    const float* ad1 = (const float*)d_in[4];
    const float* b1  = (const float*)d_in[5];
    const float* W2  = (const float*)d_in[6];
    const float* as2 = (const float*)d_in[7];
    const float* ad2 = (const float*)d_in[8];
    const float* b2  = (const float*)d_in[9];
    const float* W3  = (const float*)d_in[10];
    const float* as3 = (const float*)d_in[11];
    const float* ad3 = (const float*)d_in[12];
    const float* b3  = (const float*)d_in[13];
    float* out = (float*)d_out;

    const int n = in_sizes[0] / 3;     // 50000
    const int E = in_sizes[1] / 2;     // 400000
    const int Etot = E + n;            // with self-loops

    // workspace layout (~84 MB)
    char* ws = (char*)d_ws;
    u16* Fhi  = (u16*)ws;    ws += (size_t)n * 256 * sizeof(u16);     // 25.6 MB split hi
    u16* Flo  = (u16*)ws;    ws += (size_t)n * 256 * sizeof(u16);     // 25.6 MB split lo
    u16* Hb   = (u16*)ws;    ws += (size_t)n * 256 * sizeof(u16);     // 25.6 MB bf16 shadow
    u16* Hb3  = (u16*)ws;    ws += (size_t)n * 32 * sizeof(u16);      // 3.2 MB
    u16* B2h  = (u16*)ws;    ws += (size_t)8 * 16 * 64 * 8 * sizeof(u16);
    u16* B2l  = (u16*)ws;    ws += (size_t)8 * 16 * 64 * 8 * sizeof(u16);
    u16* B3h  = (u16*)ws;    ws += (size_t)8 * 2 * 64 * 8 * sizeof(u16);
    u16* B3l  = (u16*)ws;    ws += (size_t)8 * 2 * 64 * 8 * sizeof(u16);
    float* ssrc = (float*)ws;  ws += (size_t)n * 4 * sizeof(float);
    float* sdst = (float*)ws;  ws += (size_t)n * 4 * sizeof(float);
    float* vsd  = (float*)ws;  ws += 32 * sizeof(float);              // l1 v_s/v_d
    int* deg    = (int*)ws;    ws += (size_t)n * sizeof(int);
    int* offs   = (int*)ws;    ws += (size_t)(n + 1) * sizeof(int) + 12;
    int* cursor = (int*)ws;    ws += (size_t)n * sizeof(int);
    int* partial = (int*)ws;   ws += (size_t)128 * sizeof(int);
    int* csr    = (int*)ws;    ws += (size_t)Etot * sizeof(int);   // keep csr LAST

    // ---- CSR build (by dst) ----
    hipMemsetAsync(deg, 0, (size_t)n * sizeof(int), stream);
    int eblocks = (Etot + 255) / 256;
    edge_count<<<eblocks, 256, 0, stream>>>(ei, E, n, deg);
    int sb = (n + 1023) / 1024;
    scan_partials<<<sb, 256, 0, stream>>>(deg, partial, n);
    scan_mid<<<1, 128, 0, stream>>>(partial, sb, offs, n);
    scan_final<<<sb, 256, 0, stream>>>(deg, partial, offs, cursor, n);
    edge_fill<<<eblocks, 256, 0, stream>>>(ei, E, n, cursor, csr);

    // ---- Weight prep ----
    pack_frag<<<(8 * 16 * 64 + 255) / 256, 256, 0, stream>>>(W2, B2h, B2l, 256);
    pack_frag<<<(8 * 2 * 64 + 255) / 256, 256, 0, stream>>>(W3, B3h, B3l, 32);
    l1_prep<<<1, 256, 0, stream>>>(W1, as1, ad1, vsd);

    int nb4 = (n + 3) / 4;
    int nb128 = (n + 127) / 128;       // 391 blocks, 2/CU -> no tail

    // ---- Layer 1: 3 -> (4 x 64), concat, relu  (x-space aggregation) ----
    gat_aggregate_l1<<<nb4, 256, 0, stream>>>(x, vsd, offs, csr, W1, b1, Fhi, Flo, n);

    // ---- Layer 2: 256 -> (4 x 64), concat, relu ----
    gemm_async<16, 4><<<nb128, 512, 0, stream>>>(Fhi, Flo, B2h, B2l, as2, ad2, Hb, ssrc, sdst, n);
    gat_aggregate_m4<<<nb4, 256, 0, stream>>>(Hb, ssrc, sdst, offs, csr, b2, Fhi, Flo, n);

    // ---- Layer 3: 256 -> (1 x 32), mean(=identity), no relu ----
    gemm_async<2, 1><<<nb128, 512, 0, stream>>>(Fhi, Flo, B3h, B3l, as3, ad3, Hb3, ssrc, sdst, n);
    gat_aggregate_h1<<<nb4, 256, 0, stream>>>(Hb3, ssrc, sdst, offs, csr, b3, out, n);
}